// Round 3
// baseline (1661.706 us; speedup 1.0000x reference)
//
#include <hip/hip_runtime.h>

// ---------------- problem constants ----------------
#define NTOK 2048   // instructions
#define TT   16     // tokens per instruction
#define EE   512    // token embed dim
#define HIDD 256    // hidden
#define G4   1024   // 4*HID gate dim
#define NLVL 16
#define KLVL 128    // instrs per level
#define NBD  32     // blocks in DAG kernel
#define INV2048 (1.0f/2048.0f)

typedef _Float16 v8h __attribute__((ext_vector_type(8)));
typedef _Float16 v4h __attribute__((ext_vector_type(4)));
typedef float    v4f __attribute__((ext_vector_type(4)));

__device__ __forceinline__ v4f mfma16(v8h a, v8h b, v4f c) {
  return __builtin_amdgcn_mfma_f32_16x16x32_f16(a, b, c, 0, 0, 0);
}

__device__ __forceinline__ float fsig(float x) {
  return 1.0f / (1.0f + __expf(-x));
}
__device__ __forceinline__ float ftanh(float x) {
  float ax = fabsf(x);
  float e  = __expf(-2.0f * ax);
  float t  = (1.0f - e) / (1.0f + e);
  return copysignf(t, x);
}

// split fp32 -> (hi fp16, lo fp16 scaled by 2048)
__device__ __forceinline__ void split8(const v4f& w0, const v4f& w1, v8h& hi, v8h& lo) {
#pragma unroll
  for (int u = 0; u < 4; ++u) {
    float v = w0[u]; _Float16 h = (_Float16)v;
    hi[u] = h; lo[u] = (_Float16)((v - (float)h) * 2048.0f);
  }
#pragma unroll
  for (int u = 0; u < 4; ++u) {
    float v = w1[u]; _Float16 h = (_Float16)v;
    hi[4+u] = h; lo[4+u] = (_Float16)((v - (float)h) * 2048.0f);
  }
}

// ---------------- K-1: normalize parent_valid to uchar[16384] ---------------
// Detects device encoding: float32 (any word == 0x3F800000), packed bytes
// (any word > 1), else int32 {0,1}. Single block.
__global__ __launch_bounds__(256) void knorm(const void* __restrict__ pv_raw,
                                             unsigned char* __restrict__ pv8) {
  __shared__ int mode;   // 0 = int32, 1 = bytes, 2 = float32
  const int tid = threadIdx.x;
  if (tid == 0) mode = 0;
  __syncthreads();
  const unsigned* pu = (const unsigned*)pv_raw;
  int local = 0;
  for (int i = tid; i < 4096; i += 256) {      // first 16 KB — safe in all modes
    unsigned v = pu[i];
    if (v == 0x3F800000u) { local = 2; break; }
    if (v > 1u) local = 1;
  }
  if (local) atomicMax(&mode, local);
  __syncthreads();
  const int m = mode;
  const unsigned char* pb = (const unsigned char*)pv_raw;
  const float* pf = (const float*)pv_raw;
  const int* pi = (const int*)pv_raw;
  for (int i = tid; i < NTOK * 8; i += 256) {
    unsigned char v;
    if (m == 1)      v = (pb[i] != 0);
    else if (m == 2) v = (pf[i] != 0.0f);
    else             v = (pi[i] != 0);
    pv8[i] = v;
  }
}

// ---------------- K0: fp32 -> fp16 hi/lo weight splits (3 x [1024][256]) ----
__global__ __launch_bounds__(256) void kw_cvt(
    const float* __restrict__ a0, _Float16* __restrict__ h0, _Float16* __restrict__ l0,
    const float* __restrict__ a1, _Float16* __restrict__ h1, _Float16* __restrict__ l1,
    const float* __restrict__ a2, _Float16* __restrict__ h2, _Float16* __restrict__ l2) {
  int i = blockIdx.x * 256 + threadIdx.x;   // grid = 1024 -> exactly 262144
  if (i < HIDD * G4) {
    float v; _Float16 h;
    v = a0[i]; h = (_Float16)v; h0[i] = h; l0[i] = (_Float16)((v - (float)h) * 2048.0f);
    v = a1[i]; h = (_Float16)v; h1[i] = h; l1[i] = (_Float16)((v - (float)h) * 2048.0f);
    v = a2[i]; h = (_Float16)v; h2[i] = h; l2[i] = (_Float16)((v - (float)h) * 2048.0f);
  }
}

// ---------------- K1: Xg_half = tokens[:, t0:t0+8] @ Wih_tok^T (+biases), fp32
// A-rows within half: ar = instr*8 + (t - t0); tokrow = instr*16 + t.
// 128x128 tile, BK=64, 4 waves, 3-term split MFMA (exact to ~2e-7 rel).
__global__ __launch_bounds__(256, 2) void kg_gemm(const float* __restrict__ A,
                                                  const float* __restrict__ W,
                                                  const float* __restrict__ b1,
                                                  const float* __restrict__ b2,
                                                  float* __restrict__ Xg, int t0) {
  __shared__ _Float16 AsH[128 * 72];
  __shared__ _Float16 AsL[128 * 72];
  __shared__ _Float16 BsH[128 * 72];
  __shared__ _Float16 BsL[128 * 72];
  const int tid  = threadIdx.x;
  const int lane = tid & 63;
  const int wv   = tid >> 6;
  const int wr   = (wv >> 1) * 64;
  const int wc   = (wv & 1) * 64;
  const int mb   = blockIdx.x >> 3;
  const int nb   = blockIdx.x & 7;
  const int row0 = mb * 128;      // Xg-half row base (0..16256)
  const int col0 = nb * 128;
  const int l15  = lane & 15;
  const int lq   = lane >> 4;

  v4f acc1[4][4], acc2[4][4];
#pragma unroll
  for (int n = 0; n < 4; ++n) {
    int col  = col0 + wc + n * 16 + l15;
    float bb = b1[col] + b2[col];
#pragma unroll
    for (int m = 0; m < 4; ++m) { acc1[m][n] = (v4f){bb, bb, bb, bb}; acc2[m][n] = (v4f){0.f,0.f,0.f,0.f}; }
  }

#pragma unroll 1
  for (int kt = 0; kt < 8; ++kt) {
    const int k0 = kt * 64;
#pragma unroll
    for (int i = 0; i < 8; ++i) {
      int chunk = tid + 256 * i;            // (row 0..127, 16 chunks of 4)
      int r  = chunk >> 4;
      int c4 = (chunk & 15) * 4;
      int ar = row0 + r;
      int tokrow = ((ar >> 3) << 4) + (ar & 7) + t0;
      v4f av = *(const v4f*)(A + (size_t)tokrow * EE + k0 + c4);
      v4f bv = *(const v4f*)(W + (size_t)(col0 + r) * EE + k0 + c4);
      v4h ah, al, bh, bl;
#pragma unroll
      for (int u = 0; u < 4; ++u) {
        float v = av[u]; _Float16 h = (_Float16)v;
        ah[u] = h; al[u] = (_Float16)((v - (float)h) * 2048.0f);
        v = bv[u]; h = (_Float16)v;
        bh[u] = h; bl[u] = (_Float16)((v - (float)h) * 2048.0f);
      }
      *(v4h*)(AsH + r * 72 + c4) = ah;
      *(v4h*)(AsL + r * 72 + c4) = al;
      *(v4h*)(BsH + r * 72 + c4) = bh;
      *(v4h*)(BsL + r * 72 + c4) = bl;
    }
    __syncthreads();
#pragma unroll
    for (int kk = 0; kk < 2; ++kk) {
      const int ko = kk * 32 + lq * 8;
      v8h afh[4], afl[4], bfh[4], bfl[4];
#pragma unroll
      for (int m = 0; m < 4; ++m) {
        afh[m] = *(const v8h*)(AsH + (wr + m * 16 + l15) * 72 + ko);
        afl[m] = *(const v8h*)(AsL + (wr + m * 16 + l15) * 72 + ko);
      }
#pragma unroll
      for (int n = 0; n < 4; ++n) {
        bfh[n] = *(const v8h*)(BsH + (wc + n * 16 + l15) * 72 + ko);
        bfl[n] = *(const v8h*)(BsL + (wc + n * 16 + l15) * 72 + ko);
      }
#pragma unroll
      for (int m = 0; m < 4; ++m)
#pragma unroll
        for (int n = 0; n < 4; ++n) {
          acc1[m][n] = mfma16(afh[m], bfh[n], acc1[m][n]);
          acc2[m][n] = mfma16(afl[m], bfh[n], acc2[m][n]);
          acc2[m][n] = mfma16(afh[m], bfl[n], acc2[m][n]);
        }
    }
    __syncthreads();
  }

#pragma unroll
  for (int m = 0; m < 4; ++m)
#pragma unroll
    for (int n = 0; n < 4; ++n) {
      int row = row0 + wr + m * 16 + lq * 4;
      int col = col0 + wc + n * 16 + l15;
#pragma unroll
      for (int r = 0; r < 4; ++r)
        Xg[(size_t)(row + r) * G4 + col] = acc1[m][n][r] + acc2[m][n][r] * INV2048;
    }
}

// ---------------- K2: token LSTM recurrence, 8 steps per half ---------------
// 64 blocks x 32 rows. h in LDS (fp32), c in regs (fp32). 3-term split MFMA.
__global__ __launch_bounds__(256, 1) void kr_rec(const float* __restrict__ Xg,
                                                 const _Float16* __restrict__ WhhH,
                                                 const _Float16* __restrict__ WhhL,
                                                 float* __restrict__ Hst,
                                                 float* __restrict__ Cst,
                                                 float* __restrict__ emb, int half) {
  __shared__ float hbuf[32 * 260];   // 260 floats = 1040 B rows (16B aligned)
  const int tid  = threadIdx.x;
  const int lane = tid & 63;
  const int wv   = tid >> 6;
  const int l15  = lane & 15;
  const int lq   = lane >> 4;
  const int r0   = blockIdx.x * 32;

  v4f c[2][4];
  if (half) {
#pragma unroll
    for (int m = 0; m < 2; ++m)
#pragma unroll
      for (int j = 0; j < 4; ++j) {
        const int feat = 16 * (wv + 4 * j) + l15;
#pragma unroll
        for (int r = 0; r < 4; ++r)
          c[m][j][r] = Cst[(size_t)(r0 + m * 16 + lq * 4 + r) * HIDD + feat];
      }
#pragma unroll
    for (int it = 0; it < 32; ++it) {
      int idx = it * 256 + tid;
      hbuf[(idx >> 8) * 260 + (idx & 255)] = Hst[(size_t)(r0 + (idx >> 8)) * HIDD + (idx & 255)];
    }
  } else {
#pragma unroll
    for (int m = 0; m < 2; ++m)
#pragma unroll
      for (int j = 0; j < 4; ++j) c[m][j] = (v4f){0.f, 0.f, 0.f, 0.f};
  }
  __syncthreads();

#pragma unroll 1
  for (int tl = 0; tl < 8; ++tl) {
    const bool have_h = half || (tl > 0);
    v4f g1[2][4][4], g2[2][4][4];
    // init g1 = precomputed input projection (fp32, includes biases), g2 = 0
#pragma unroll
    for (int m = 0; m < 2; ++m)
#pragma unroll
      for (int g = 0; g < 4; ++g)
#pragma unroll
        for (int j = 0; j < 4; ++j) {
          const int col = 256 * g + 16 * (wv + 4 * j) + l15;
#pragma unroll
          for (int r = 0; r < 4; ++r) {
            const size_t ar = (size_t)(r0 + m * 16 + lq * 4 + r) * 8 + tl;
            g1[m][g][j][r] = Xg[ar * G4 + col];
          }
          g2[m][g][j] = (v4f){0.f, 0.f, 0.f, 0.f};
        }
    if (have_h) {
#pragma unroll 1
      for (int kk = 0; kk < 8; ++kk) {
        const int ko = kk * 32 + lq * 8;
        v4f w0 = *(const v4f*)(hbuf + l15 * 260 + ko);
        v4f w1 = *(const v4f*)(hbuf + l15 * 260 + ko + 4);
        v4f w2 = *(const v4f*)(hbuf + (16 + l15) * 260 + ko);
        v4f w3 = *(const v4f*)(hbuf + (16 + l15) * 260 + ko + 4);
        v8h a0h, a0l, a1h, a1l;
        split8(w0, w1, a0h, a0l);
        split8(w2, w3, a1h, a1l);
#pragma unroll
        for (int g = 0; g < 4; ++g)
#pragma unroll
          for (int j = 0; j < 4; ++j) {
            const int fc = 16 * g + wv + 4 * j;
            v8h bh = *(const v8h*)(WhhH + (size_t)(16 * fc + l15) * HIDD + ko);
            v8h bl = *(const v8h*)(WhhL + (size_t)(16 * fc + l15) * HIDD + ko);
            g1[0][g][j] = mfma16(a0h, bh, g1[0][g][j]);
            g2[0][g][j] = mfma16(a0l, bh, g2[0][g][j]);
            g2[0][g][j] = mfma16(a0h, bl, g2[0][g][j]);
            g1[1][g][j] = mfma16(a1h, bh, g1[1][g][j]);
            g2[1][g][j] = mfma16(a1l, bh, g2[1][g][j]);
            g2[1][g][j] = mfma16(a1h, bl, g2[1][g][j]);
          }
      }
    }
    __syncthreads();   // all hbuf reads done before overwrite
#pragma unroll
    for (int m = 0; m < 2; ++m)
#pragma unroll
      for (int j = 0; j < 4; ++j) {
        const int feat = 16 * (wv + 4 * j) + l15;
#pragma unroll
        for (int r = 0; r < 4; ++r) {
          const int rr = m * 16 + lq * 4 + r;
          float ig = g1[m][0][j][r] + g2[m][0][j][r] * INV2048;
          float fg = g1[m][1][j][r] + g2[m][1][j][r] * INV2048;
          float gg = g1[m][2][j][r] + g2[m][2][j][r] * INV2048;
          float og = g1[m][3][j][r] + g2[m][3][j][r] * INV2048;
          float cn = fsig(fg) * c[m][j][r] + fsig(ig) * ftanh(gg);
          float hn = fsig(og) * ftanh(cn);
          c[m][j][r] = cn;
          hbuf[rr * 260 + feat] = hn;
          if (tl == 7) {
            const size_t grow = r0 + rr;
            if (!half) { Hst[grow * HIDD + feat] = hn; Cst[grow * HIDD + feat] = cn; }
            else       { emb[grow * HIDD + feat] = hn; }
          }
        }
      }
    __syncthreads();   // writes visible before next step's reads
  }
}

// ---------------- K3: DAG LSTM (16 levels) + root max + linear --------------
__device__ __forceinline__ void gbar(unsigned* cnt, unsigned target) {
  __syncthreads();
  if (threadIdx.x == 0) {
    __threadfence();
    __hip_atomic_fetch_add(cnt, 1u, __ATOMIC_RELEASE, __HIP_MEMORY_SCOPE_AGENT);
    while (__hip_atomic_load(cnt, __ATOMIC_ACQUIRE, __HIP_MEMORY_SCOPE_AGENT) < target) {
      __builtin_amdgcn_s_sleep(4);
    }
    __threadfence();   // reader-side: invalidate caches before block proceeds
  }
  __syncthreads();
}

__global__ __launch_bounds__(256, 1) void kd_dag(const float* __restrict__ emb,
    const _Float16* __restrict__ WihH, const _Float16* __restrict__ WihL,
    const _Float16* __restrict__ WhhH, const _Float16* __restrict__ WhhL,
    const float* __restrict__ bi, const float* __restrict__ bh,
    const int* __restrict__ pidx, const unsigned char* __restrict__ pval,
    const float* __restrict__ Wlin, const float* __restrict__ blin,
    float* __restrict__ H, float* __restrict__ C,
    int* __restrict__ appears, float* __restrict__ pmax,
    unsigned* __restrict__ barcnt, float* __restrict__ out) {
  __shared__ float h0s[16 * 260];
  __shared__ float c0s[16 * 260];
  __shared__ int      pis[128];
  __shared__ unsigned char pvs[128];
  __shared__ float    red[256];
  const int tid  = threadIdx.x;
  const int lane = tid & 63;
  const int wv   = tid >> 6;
  const int l15  = lane & 15;
  const int lq   = lane >> 4;
  const int b    = blockIdx.x;
  const int mf   = b >> 2;       // m-frag 0..7 (16 rows of the level)
  const int q    = b & 3;        // gate-col quarter
  const int fi   = q * 4 + wv;   // within-gate frag index 0..15
  unsigned phc = 0;

  // scatter "appears" (appears[] zeroed by hipMemsetAsync before this kernel)
  {
    int e = b * 512 + tid * 2;
#pragma unroll
    for (int u = 0; u < 2; ++u, ++e) {
      int row = e >> 3, p = e & 7;
      if (pval[row * 8 + p]) atomicAdd(appears + pidx[row * 8 + p], 1);
    }
  }

#pragma unroll 1
  for (int l = 0; l < NLVL; ++l) {
    if (tid < 128) {
      int rr = tid >> 3, p = tid & 7;
      int row = l * KLVL + mf * 16 + rr;
      pis[tid] = pidx[row * 8 + p];
      pvs[tid] = pval[row * 8 + p];
    }
    __syncthreads();
    // gather parent max into LDS: 16 rows x 64 float4 chunks (fp32)
#pragma unroll 1
    for (int it = 0; it < 4; ++it) {
      int task = tid + 256 * it;
      int rr = task >> 6;
      int f4 = (task & 63) * 4;
      v4f hm = (v4f){-1e30f, -1e30f, -1e30f, -1e30f};
      v4f cm = hm;
      bool any = false;
#pragma unroll
      for (int p = 0; p < 8; ++p) {
        if (pvs[rr * 8 + p]) {
          any = true;
          int par = pis[rr * 8 + p];
          v4f hv = *(const v4f*)(H + (size_t)par * HIDD + f4);
          v4f cv = *(const v4f*)(C + (size_t)par * HIDD + f4);
#pragma unroll
          for (int u = 0; u < 4; ++u) { hm[u] = fmaxf(hm[u], hv[u]); cm[u] = fmaxf(cm[u], cv[u]); }
        }
      }
      if (!any) { hm = (v4f){0.f,0.f,0.f,0.f}; cm = (v4f){0.f,0.f,0.f,0.f}; }
      *(v4f*)(h0s + rr * 260 + f4) = hm;
      *(v4f*)(c0s + rr * 260 + f4) = cm;
    }
    __syncthreads();

    v4f acc1[4], acc2[4];
#pragma unroll
    for (int g = 0; g < 4; ++g) {
      int col  = 256 * g + 16 * fi + l15;
      float bb = bi[col] + bh[col];
      acc1[g] = (v4f){bb, bb, bb, bb};
      acc2[g] = (v4f){0.f, 0.f, 0.f, 0.f};
    }
    const int arow = l * KLVL + mf * 16 + l15;
#pragma unroll 1
    for (int kk = 0; kk < 8; ++kk) {   // x @ Wih^T
      const int ko = kk * 32 + lq * 8;
      v4f x0 = *(const v4f*)(emb + (size_t)arow * HIDD + ko);
      v4f x1 = *(const v4f*)(emb + (size_t)arow * HIDD + ko + 4);
      v8h axh, axl;
      split8(x0, x1, axh, axl);
#pragma unroll
      for (int g = 0; g < 4; ++g) {
        int n = 256 * g + 16 * fi + l15;
        v8h bh8 = *(const v8h*)(WihH + (size_t)n * HIDD + ko);
        v8h bl8 = *(const v8h*)(WihL + (size_t)n * HIDD + ko);
        acc1[g] = mfma16(axh, bh8, acc1[g]);
        acc2[g] = mfma16(axl, bh8, acc2[g]);
        acc2[g] = mfma16(axh, bl8, acc2[g]);
      }
    }
#pragma unroll 1
    for (int kk = 0; kk < 8; ++kk) {   // h0 @ Whh^T
      const int ko = kk * 32 + lq * 8;
      v4f h0 = *(const v4f*)(h0s + l15 * 260 + ko);
      v4f h1 = *(const v4f*)(h0s + l15 * 260 + ko + 4);
      v8h ahh, ahl;
      split8(h0, h1, ahh, ahl);
#pragma unroll
      for (int g = 0; g < 4; ++g) {
        int n = 256 * g + 16 * fi + l15;
        v8h bh8 = *(const v8h*)(WhhH + (size_t)n * HIDD + ko);
        v8h bl8 = *(const v8h*)(WhhL + (size_t)n * HIDD + ko);
        acc1[g] = mfma16(ahh, bh8, acc1[g]);
        acc2[g] = mfma16(ahl, bh8, acc2[g]);
        acc2[g] = mfma16(ahh, bl8, acc2[g]);
      }
    }
#pragma unroll
    for (int r = 0; r < 4; ++r) {
      int rr = lq * 4 + r;
      int n  = 16 * fi + l15;
      float ig = acc1[0][r] + acc2[0][r] * INV2048;
      float fg = acc1[1][r] + acc2[1][r] * INV2048;
      float gg = acc1[2][r] + acc2[2][r] * INV2048;
      float og = acc1[3][r] + acc2[3][r] * INV2048;
      float c0 = c0s[rr * 260 + n];
      float cn = fsig(fg) * c0 + fsig(ig) * ftanh(gg);
      float hn = fsig(og) * ftanh(cn);
      int grow = l * KLVL + mf * 16 + rr;
      H[(size_t)grow * HIDD + n] = hn;
      C[(size_t)grow * HIDD + n] = cn;
    }
    gbar(barcnt, ++phc * NBD);
  }

  // per-block partial root max (64 rows each), feat = tid
  {
    int rb = b * 64;
    float m = -1e30f;
#pragma unroll 1
    for (int r = 0; r < 64; ++r) {
      int row = rb + r;
      if (appears[row] == 0) m = fmaxf(m, H[(size_t)row * HIDD + tid]);
    }
    pmax[b * 256 + tid] = m;
  }
  gbar(barcnt, ++phc * NBD);

  if (b == 0) {
    float m = pmax[tid];
#pragma unroll 1
    for (int bb = 1; bb < NBD; ++bb) m = fmaxf(m, pmax[bb * 256 + tid]);
    red[tid] = m * Wlin[tid];
    __syncthreads();
    if (tid == 0) {
      float s = 0.f;
      for (int i2 = 0; i2 < 256; ++i2) s += red[i2];
      out[0] = s + blin[0];
    }
  }
}

// ---------------- launch ----------------------------------------------------
extern "C" void kernel_launch(void* const* d_in, const int* in_sizes, int n_in,
                              void* d_out, int out_size, void* d_ws, size_t ws_size,
                              hipStream_t stream) {
  const float* tokens  = (const float*)d_in[0];
  const int*   pidx    = (const int*)d_in[1];
  const void*  pvraw   = (const void*)d_in[2];   // bool -> encoding detected on device
  const float* Wih_tok = (const float*)d_in[3];
  const float* Whh_tok = (const float*)d_in[4];
  const float* bih_tok = (const float*)d_in[5];
  const float* bhh_tok = (const float*)d_in[6];
  const float* Wih_ins = (const float*)d_in[7];
  const float* Whh_ins = (const float*)d_in[8];
  const float* bih_ins = (const float*)d_in[9];
  const float* bhh_ins = (const float*)d_in[10];
  const float* Wlin    = (const float*)d_in[11];
  const float* blin    = (const float*)d_in[12];

  char* ws = (char*)d_ws;
  const size_t OFF_XG   = 0;                        // 16384*1024*4 = 67108864 (one t-half, reused)
  const size_t OFF_H    = OFF_XG   + 67108864;      // 2048*256*4
  const size_t OFF_C    = OFF_H    + 2097152;
  const size_t OFF_EMB  = OFF_C    + 2097152;       // fp32 2048*256*4
  const size_t OFF_WHH_H  = OFF_EMB   + 2097152;    // 1024*256*2 each
  const size_t OFF_WHH_L  = OFF_WHH_H  + 524288;
  const size_t OFF_WIHI_H = OFF_WHH_L  + 524288;
  const size_t OFF_WIHI_L = OFF_WIHI_H + 524288;
  const size_t OFF_WHHI_H = OFF_WIHI_L + 524288;
  const size_t OFF_WHHI_L = OFF_WHHI_H + 524288;
  const size_t OFF_APP  = OFF_WHHI_L + 524288;      // 2048*4
  const size_t OFF_BAR  = OFF_APP + 8192;           // 256 B
  const size_t OFF_PMX  = OFF_BAR + 256;            // 32*256*4 = 32768
  const size_t OFF_PV8  = OFF_PMX + 32768;          // 16384 B normalized bool

  float*    Xg    = (float*)(ws + OFF_XG);
  float*    Hbuf  = (float*)(ws + OFF_H);
  float*    Cbuf  = (float*)(ws + OFF_C);
  float*    emb   = (float*)(ws + OFF_EMB);
  _Float16* WhhH  = (_Float16*)(ws + OFF_WHH_H);
  _Float16* WhhL  = (_Float16*)(ws + OFF_WHH_L);
  _Float16* WihIH = (_Float16*)(ws + OFF_WIHI_H);
  _Float16* WihIL = (_Float16*)(ws + OFF_WIHI_L);
  _Float16* WhhIH = (_Float16*)(ws + OFF_WHHI_H);
  _Float16* WhhIL = (_Float16*)(ws + OFF_WHHI_L);
  int*      app   = (int*)(ws + OFF_APP);
  unsigned* bar   = (unsigned*)(ws + OFF_BAR);
  float*    pmx   = (float*)(ws + OFF_PMX);
  unsigned char* pv8 = (unsigned char*)(ws + OFF_PV8);

  // zero appears + barrier counter (graph-capture-safe)
  hipMemsetAsync(ws + OFF_APP, 0, 8192 + 256, stream);

  knorm<<<dim3(1), dim3(256), 0, stream>>>(pvraw, pv8);
  kw_cvt<<<dim3(1024), dim3(256), 0, stream>>>(Whh_tok, WhhH, WhhL,
                                               Wih_ins, WihIH, WihIL,
                                               Whh_ins, WhhIH, WhhIL);
  // half 0: t = 0..7
  kg_gemm<<<dim3(1024), dim3(256), 0, stream>>>(tokens, Wih_tok, bih_tok, bhh_tok, Xg, 0);
  kr_rec<<<dim3(64), dim3(256), 0, stream>>>(Xg, WhhH, WhhL, Hbuf, Cbuf, emb, 0);
  // half 1: t = 8..15 (reuses Xg buffer)
  kg_gemm<<<dim3(1024), dim3(256), 0, stream>>>(tokens, Wih_tok, bih_tok, bhh_tok, Xg, 8);
  kr_rec<<<dim3(64), dim3(256), 0, stream>>>(Xg, WhhH, WhhL, Hbuf, Cbuf, emb, 1);

  kd_dag<<<dim3(NBD), dim3(256), 0, stream>>>(emb, WihIH, WihIL, WhhIH, WhhIL,
                                              bih_ins, bhh_ins, pidx, pv8, Wlin, blin,
                                              Hbuf, Cbuf, app, pmx, bar, (float*)d_out);
}

// Round 4
// 1626.969 us; speedup vs baseline: 1.0214x; 1.0214x over previous
//
#include <hip/hip_runtime.h>

// ---------------- problem constants ----------------
#define NTOK 2048   // instructions
#define TT   16     // tokens per instruction
#define EE   512    // token embed dim
#define HIDD 256    // hidden
#define G4   1024   // 4*HID gate dim
#define NLVL 16
#define KLVL 128    // instrs per level
#define INV2048 (1.0f/2048.0f)

typedef _Float16 v8h __attribute__((ext_vector_type(8)));
typedef _Float16 v4h __attribute__((ext_vector_type(4)));
typedef float    v4f __attribute__((ext_vector_type(4)));

__device__ __forceinline__ v4f mfma16(v8h a, v8h b, v4f c) {
  return __builtin_amdgcn_mfma_f32_16x16x32_f16(a, b, c, 0, 0, 0);
}

__device__ __forceinline__ float fsig(float x) {
  return 1.0f / (1.0f + __expf(-x));
}
__device__ __forceinline__ float ftanh(float x) {
  float ax = fabsf(x);
  float e  = __expf(-2.0f * ax);
  float t  = (1.0f - e) / (1.0f + e);
  return copysignf(t, x);
}

// split fp32 -> (hi fp16, lo fp16 scaled by 2048)
__device__ __forceinline__ void split8(const v4f& w0, const v4f& w1, v8h& hi, v8h& lo) {
#pragma unroll
  for (int u = 0; u < 4; ++u) {
    float v = w0[u]; _Float16 h = (_Float16)v;
    hi[u] = h; lo[u] = (_Float16)((v - (float)h) * 2048.0f);
  }
#pragma unroll
  for (int u = 0; u < 4; ++u) {
    float v = w1[u]; _Float16 h = (_Float16)v;
    hi[4+u] = h; lo[4+u] = (_Float16)((v - (float)h) * 2048.0f);
  }
}

// ---------------- K-1: normalize parent_valid to uchar[16384] ---------------
// Device encoding detected: int32 {0,1} (confirmed r3), but keep the detector
// (cheap, robust): float32 (word == 0x3F800000), packed bytes (word > 1), else int32.
__global__ __launch_bounds__(256) void knorm(const void* __restrict__ pv_raw,
                                             unsigned char* __restrict__ pv8) {
  __shared__ int mode;   // 0 = int32, 1 = bytes, 2 = float32
  const int tid = threadIdx.x;
  if (tid == 0) mode = 0;
  __syncthreads();
  const unsigned* pu = (const unsigned*)pv_raw;
  int local = 0;
  for (int i = tid; i < 4096; i += 256) {
    unsigned v = pu[i];
    if (v == 0x3F800000u) { local = 2; break; }
    if (v > 1u) local = 1;
  }
  if (local) atomicMax(&mode, local);
  __syncthreads();
  const int m = mode;
  const unsigned char* pb = (const unsigned char*)pv_raw;
  const float* pf = (const float*)pv_raw;
  const int* pi = (const int*)pv_raw;
  for (int i = tid; i < NTOK * 8; i += 256) {
    unsigned char v;
    if (m == 1)      v = (pb[i] != 0);
    else if (m == 2) v = (pf[i] != 0.0f);
    else             v = (pi[i] != 0);
    pv8[i] = v;
  }
}

// ---------------- K0: fp32 -> fp16 hi/lo weight splits (3 x [1024][256]) ----
__global__ __launch_bounds__(256) void kw_cvt(
    const float* __restrict__ a0, _Float16* __restrict__ h0, _Float16* __restrict__ l0,
    const float* __restrict__ a1, _Float16* __restrict__ h1, _Float16* __restrict__ l1,
    const float* __restrict__ a2, _Float16* __restrict__ h2, _Float16* __restrict__ l2) {
  int i = blockIdx.x * 256 + threadIdx.x;
  if (i < HIDD * G4) {
    float v; _Float16 h;
    v = a0[i]; h = (_Float16)v; h0[i] = h; l0[i] = (_Float16)((v - (float)h) * 2048.0f);
    v = a1[i]; h = (_Float16)v; h1[i] = h; l1[i] = (_Float16)((v - (float)h) * 2048.0f);
    v = a2[i]; h = (_Float16)v; h2[i] = h; l2[i] = (_Float16)((v - (float)h) * 2048.0f);
  }
}

// ---------------- K1: Xg_half = tokens[:, t0:t0+8] @ Wih_tok^T (+biases), fp32
__global__ __launch_bounds__(256, 2) void kg_gemm(const float* __restrict__ A,
                                                  const float* __restrict__ W,
                                                  const float* __restrict__ b1,
                                                  const float* __restrict__ b2,
                                                  float* __restrict__ Xg, int t0) {
  __shared__ _Float16 AsH[128 * 72];
  __shared__ _Float16 AsL[128 * 72];
  __shared__ _Float16 BsH[128 * 72];
  __shared__ _Float16 BsL[128 * 72];
  const int tid  = threadIdx.x;
  const int lane = tid & 63;
  const int wv   = tid >> 6;
  const int wr   = (wv >> 1) * 64;
  const int wc   = (wv & 1) * 64;
  const int mb   = blockIdx.x >> 3;
  const int nb   = blockIdx.x & 7;
  const int row0 = mb * 128;
  const int col0 = nb * 128;
  const int l15  = lane & 15;
  const int lq   = lane >> 4;

  v4f acc1[4][4], acc2[4][4];
#pragma unroll
  for (int n = 0; n < 4; ++n) {
    int col  = col0 + wc + n * 16 + l15;
    float bb = b1[col] + b2[col];
#pragma unroll
    for (int m = 0; m < 4; ++m) { acc1[m][n] = (v4f){bb, bb, bb, bb}; acc2[m][n] = (v4f){0.f,0.f,0.f,0.f}; }
  }

#pragma unroll 1
  for (int kt = 0; kt < 8; ++kt) {
    const int k0 = kt * 64;
#pragma unroll
    for (int i = 0; i < 8; ++i) {
      int chunk = tid + 256 * i;
      int r  = chunk >> 4;
      int c4 = (chunk & 15) * 4;
      int ar = row0 + r;
      int tokrow = ((ar >> 3) << 4) + (ar & 7) + t0;
      v4f av = *(const v4f*)(A + (size_t)tokrow * EE + k0 + c4);
      v4f bv = *(const v4f*)(W + (size_t)(col0 + r) * EE + k0 + c4);
      v4h ah, al, bh, bl;
#pragma unroll
      for (int u = 0; u < 4; ++u) {
        float v = av[u]; _Float16 h = (_Float16)v;
        ah[u] = h; al[u] = (_Float16)((v - (float)h) * 2048.0f);
        v = bv[u]; h = (_Float16)v;
        bh[u] = h; bl[u] = (_Float16)((v - (float)h) * 2048.0f);
      }
      *(v4h*)(AsH + r * 72 + c4) = ah;
      *(v4h*)(AsL + r * 72 + c4) = al;
      *(v4h*)(BsH + r * 72 + c4) = bh;
      *(v4h*)(BsL + r * 72 + c4) = bl;
    }
    __syncthreads();
#pragma unroll
    for (int kk = 0; kk < 2; ++kk) {
      const int ko = kk * 32 + lq * 8;
      v8h afh[4], afl[4], bfh[4], bfl[4];
#pragma unroll
      for (int m = 0; m < 4; ++m) {
        afh[m] = *(const v8h*)(AsH + (wr + m * 16 + l15) * 72 + ko);
        afl[m] = *(const v8h*)(AsL + (wr + m * 16 + l15) * 72 + ko);
      }
#pragma unroll
      for (int n = 0; n < 4; ++n) {
        bfh[n] = *(const v8h*)(BsH + (wc + n * 16 + l15) * 72 + ko);
        bfl[n] = *(const v8h*)(BsL + (wc + n * 16 + l15) * 72 + ko);
      }
#pragma unroll
      for (int m = 0; m < 4; ++m)
#pragma unroll
        for (int n = 0; n < 4; ++n) {
          acc1[m][n] = mfma16(afh[m], bfh[n], acc1[m][n]);
          acc2[m][n] = mfma16(afl[m], bfh[n], acc2[m][n]);
          acc2[m][n] = mfma16(afh[m], bfl[n], acc2[m][n]);
        }
    }
    __syncthreads();
  }

#pragma unroll
  for (int m = 0; m < 4; ++m)
#pragma unroll
    for (int n = 0; n < 4; ++n) {
      int row = row0 + wr + m * 16 + lq * 4;
      int col = col0 + wc + n * 16 + l15;
#pragma unroll
      for (int r = 0; r < 4; ++r)
        Xg[(size_t)(row + r) * G4 + col] = acc1[m][n][r] + acc2[m][n][r] * INV2048;
    }
}

// ---------------- K2: token LSTM recurrence, 8 steps per half ---------------
__global__ __launch_bounds__(256, 1) void kr_rec(const float* __restrict__ Xg,
                                                 const _Float16* __restrict__ WhhH,
                                                 const _Float16* __restrict__ WhhL,
                                                 float* __restrict__ Hst,
                                                 float* __restrict__ Cst,
                                                 float* __restrict__ emb, int half) {
  __shared__ float hbuf[32 * 260];
  const int tid  = threadIdx.x;
  const int lane = tid & 63;
  const int wv   = tid >> 6;
  const int l15  = lane & 15;
  const int lq   = lane >> 4;
  const int r0   = blockIdx.x * 32;

  v4f c[2][4];
  if (half) {
#pragma unroll
    for (int m = 0; m < 2; ++m)
#pragma unroll
      for (int j = 0; j < 4; ++j) {
        const int feat = 16 * (wv + 4 * j) + l15;
#pragma unroll
        for (int r = 0; r < 4; ++r)
          c[m][j][r] = Cst[(size_t)(r0 + m * 16 + lq * 4 + r) * HIDD + feat];
      }
#pragma unroll
    for (int it = 0; it < 32; ++it) {
      int idx = it * 256 + tid;
      hbuf[(idx >> 8) * 260 + (idx & 255)] = Hst[(size_t)(r0 + (idx >> 8)) * HIDD + (idx & 255)];
    }
  } else {
#pragma unroll
    for (int m = 0; m < 2; ++m)
#pragma unroll
      for (int j = 0; j < 4; ++j) c[m][j] = (v4f){0.f, 0.f, 0.f, 0.f};
  }
  __syncthreads();

#pragma unroll 1
  for (int tl = 0; tl < 8; ++tl) {
    const bool have_h = half || (tl > 0);
    v4f g1[2][4][4], g2[2][4][4];
#pragma unroll
    for (int m = 0; m < 2; ++m)
#pragma unroll
      for (int g = 0; g < 4; ++g)
#pragma unroll
        for (int j = 0; j < 4; ++j) {
          const int col = 256 * g + 16 * (wv + 4 * j) + l15;
#pragma unroll
          for (int r = 0; r < 4; ++r) {
            const size_t ar = (size_t)(r0 + m * 16 + lq * 4 + r) * 8 + tl;
            g1[m][g][j][r] = Xg[ar * G4 + col];
          }
          g2[m][g][j] = (v4f){0.f, 0.f, 0.f, 0.f};
        }
    if (have_h) {
#pragma unroll 1
      for (int kk = 0; kk < 8; ++kk) {
        const int ko = kk * 32 + lq * 8;
        v4f w0 = *(const v4f*)(hbuf + l15 * 260 + ko);
        v4f w1 = *(const v4f*)(hbuf + l15 * 260 + ko + 4);
        v4f w2 = *(const v4f*)(hbuf + (16 + l15) * 260 + ko);
        v4f w3 = *(const v4f*)(hbuf + (16 + l15) * 260 + ko + 4);
        v8h a0h, a0l, a1h, a1l;
        split8(w0, w1, a0h, a0l);
        split8(w2, w3, a1h, a1l);
#pragma unroll
        for (int g = 0; g < 4; ++g)
#pragma unroll
          for (int j = 0; j < 4; ++j) {
            const int fc = 16 * g + wv + 4 * j;
            v8h bh = *(const v8h*)(WhhH + (size_t)(16 * fc + l15) * HIDD + ko);
            v8h bl = *(const v8h*)(WhhL + (size_t)(16 * fc + l15) * HIDD + ko);
            g1[0][g][j] = mfma16(a0h, bh, g1[0][g][j]);
            g2[0][g][j] = mfma16(a0l, bh, g2[0][g][j]);
            g2[0][g][j] = mfma16(a0h, bl, g2[0][g][j]);
            g1[1][g][j] = mfma16(a1h, bh, g1[1][g][j]);
            g2[1][g][j] = mfma16(a1l, bh, g2[1][g][j]);
            g2[1][g][j] = mfma16(a1h, bl, g2[1][g][j]);
          }
      }
    }
    __syncthreads();
#pragma unroll
    for (int m = 0; m < 2; ++m)
#pragma unroll
      for (int j = 0; j < 4; ++j) {
        const int feat = 16 * (wv + 4 * j) + l15;
#pragma unroll
        for (int r = 0; r < 4; ++r) {
          const int rr = m * 16 + lq * 4 + r;
          float ig = g1[m][0][j][r] + g2[m][0][j][r] * INV2048;
          float fg = g1[m][1][j][r] + g2[m][1][j][r] * INV2048;
          float gg = g1[m][2][j][r] + g2[m][2][j][r] * INV2048;
          float og = g1[m][3][j][r] + g2[m][3][j][r] * INV2048;
          float cn = fsig(fg) * c[m][j][r] + fsig(ig) * ftanh(gg);
          float hn = fsig(og) * ftanh(cn);
          c[m][j][r] = cn;
          hbuf[rr * 260 + feat] = hn;
          if (tl == 7) {
            const size_t grow = r0 + rr;
            if (!half) { Hst[grow * HIDD + feat] = hn; Cst[grow * HIDD + feat] = cn; }
            else       { emb[grow * HIDD + feat] = hn; }
          }
        }
      }
    __syncthreads();
  }
}

// ---------------- K3a: appears scatter (32 blocks) --------------------------
__global__ __launch_bounds__(256) void kapp(const int* __restrict__ pidx,
                                            const unsigned char* __restrict__ pval,
                                            int* __restrict__ appears) {
  int e = blockIdx.x * 512 + threadIdx.x * 2;
#pragma unroll
  for (int u = 0; u < 2; ++u, ++e) {
    if (pval[e]) atomicAdd(appears + pidx[e], 1);
  }
}

// ---------------- K3b: one DAG level (32 blocks, no grid sync) --------------
// block b: mf = b>>2 (16 rows of the level), q = b&3 (gate-col quarter).
__global__ __launch_bounds__(256) void klevel(
    const float* __restrict__ emb,
    const _Float16* __restrict__ WihH, const _Float16* __restrict__ WihL,
    const _Float16* __restrict__ WhhH, const _Float16* __restrict__ WhhL,
    const float* __restrict__ bi, const float* __restrict__ bh,
    const int* __restrict__ pidx, const unsigned char* __restrict__ pval,
    float* __restrict__ H, float* __restrict__ C, int l) {
  __shared__ float h0s[16 * 260];
  __shared__ float c0s[16 * 260];
  __shared__ int      pis[128];
  __shared__ unsigned char pvs[128];
  const int tid  = threadIdx.x;
  const int lane = tid & 63;
  const int wv   = tid >> 6;
  const int l15  = lane & 15;
  const int lq   = lane >> 4;
  const int b    = blockIdx.x;
  const int mf   = b >> 2;
  const int q    = b & 3;
  const int fi   = q * 4 + wv;

  if (tid < 128) {
    int rr = tid >> 3, p = tid & 7;
    int row = l * KLVL + mf * 16 + rr;
    pis[tid] = pidx[row * 8 + p];
    pvs[tid] = pval[row * 8 + p];
  }
  __syncthreads();
  // gather parent max into LDS: 16 rows x 64 float4 chunks (fp32)
#pragma unroll 1
  for (int it = 0; it < 4; ++it) {
    int task = tid + 256 * it;
    int rr = task >> 6;
    int f4 = (task & 63) * 4;
    v4f hm = (v4f){-1e30f, -1e30f, -1e30f, -1e30f};
    v4f cm = hm;
    bool any = false;
#pragma unroll
    for (int p = 0; p < 8; ++p) {
      if (pvs[rr * 8 + p]) {
        any = true;
        int par = pis[rr * 8 + p];
        v4f hv = *(const v4f*)(H + (size_t)par * HIDD + f4);
        v4f cv = *(const v4f*)(C + (size_t)par * HIDD + f4);
#pragma unroll
        for (int u = 0; u < 4; ++u) { hm[u] = fmaxf(hm[u], hv[u]); cm[u] = fmaxf(cm[u], cv[u]); }
      }
    }
    if (!any) { hm = (v4f){0.f,0.f,0.f,0.f}; cm = (v4f){0.f,0.f,0.f,0.f}; }
    *(v4f*)(h0s + rr * 260 + f4) = hm;
    *(v4f*)(c0s + rr * 260 + f4) = cm;
  }
  __syncthreads();

  v4f acc1[4], acc2[4];
#pragma unroll
  for (int g = 0; g < 4; ++g) {
    int col  = 256 * g + 16 * fi + l15;
    float bb = bi[col] + bh[col];
    acc1[g] = (v4f){bb, bb, bb, bb};
    acc2[g] = (v4f){0.f, 0.f, 0.f, 0.f};
  }
  const int arow = l * KLVL + mf * 16 + l15;
#pragma unroll 1
  for (int kk = 0; kk < 8; ++kk) {   // x @ Wih^T
    const int ko = kk * 32 + lq * 8;
    v4f x0 = *(const v4f*)(emb + (size_t)arow * HIDD + ko);
    v4f x1 = *(const v4f*)(emb + (size_t)arow * HIDD + ko + 4);
    v8h axh, axl;
    split8(x0, x1, axh, axl);
#pragma unroll
    for (int g = 0; g < 4; ++g) {
      int n = 256 * g + 16 * fi + l15;
      v8h bh8 = *(const v8h*)(WihH + (size_t)n * HIDD + ko);
      v8h bl8 = *(const v8h*)(WihL + (size_t)n * HIDD + ko);
      acc1[g] = mfma16(axh, bh8, acc1[g]);
      acc2[g] = mfma16(axl, bh8, acc2[g]);
      acc2[g] = mfma16(axh, bl8, acc2[g]);
    }
  }
#pragma unroll 1
  for (int kk = 0; kk < 8; ++kk) {   // h0 @ Whh^T
    const int ko = kk * 32 + lq * 8;
    v4f h0 = *(const v4f*)(h0s + l15 * 260 + ko);
    v4f h1 = *(const v4f*)(h0s + l15 * 260 + ko + 4);
    v8h ahh, ahl;
    split8(h0, h1, ahh, ahl);
#pragma unroll
    for (int g = 0; g < 4; ++g) {
      int n = 256 * g + 16 * fi + l15;
      v8h bh8 = *(const v8h*)(WhhH + (size_t)n * HIDD + ko);
      v8h bl8 = *(const v8h*)(WhhL + (size_t)n * HIDD + ko);
      acc1[g] = mfma16(ahh, bh8, acc1[g]);
      acc2[g] = mfma16(ahl, bh8, acc2[g]);
      acc2[g] = mfma16(ahh, bl8, acc2[g]);
    }
  }
#pragma unroll
  for (int r = 0; r < 4; ++r) {
    int rr = lq * 4 + r;
    int n  = 16 * fi + l15;
    float ig = acc1[0][r] + acc2[0][r] * INV2048;
    float fg = acc1[1][r] + acc2[1][r] * INV2048;
    float gg = acc1[2][r] + acc2[2][r] * INV2048;
    float og = acc1[3][r] + acc2[3][r] * INV2048;
    float c0 = c0s[rr * 260 + n];
    float cn = fsig(fg) * c0 + fsig(ig) * ftanh(gg);
    float hn = fsig(og) * ftanh(cn);
    int grow = l * KLVL + mf * 16 + rr;
    H[(size_t)grow * HIDD + n] = hn;
    C[(size_t)grow * HIDD + n] = cn;
  }
}

// ---------------- K4a: partial root max (32 blocks x 64 rows) ---------------
__global__ __launch_bounds__(256) void kroot1(const float* __restrict__ H,
                                              const int* __restrict__ appears,
                                              float* __restrict__ pmax) {
  __shared__ int app[64];
  const int tid = threadIdx.x;
  const int rb  = blockIdx.x * 64;
  if (tid < 64) app[tid] = appears[rb + tid];
  __syncthreads();
  float m = -1e30f;
#pragma unroll 1
  for (int r = 0; r < 64; ++r) {
    if (app[r] == 0) m = fmaxf(m, H[(size_t)(rb + r) * HIDD + tid]);
  }
  pmax[blockIdx.x * 256 + tid] = m;
}

// ---------------- K4b: final combine + linear -------------------------------
__global__ __launch_bounds__(256) void kroot2(const float* __restrict__ pmax,
                                              const float* __restrict__ Wlin,
                                              const float* __restrict__ blin,
                                              float* __restrict__ out) {
  __shared__ float red[256];
  const int tid = threadIdx.x;
  float m = pmax[tid];
#pragma unroll 1
  for (int bb = 1; bb < 32; ++bb) m = fmaxf(m, pmax[bb * 256 + tid]);
  red[tid] = m * Wlin[tid];
  __syncthreads();
  if (tid == 0) {
    float s = 0.f;
    for (int i2 = 0; i2 < 256; ++i2) s += red[i2];
    out[0] = s + blin[0];
  }
}

// ---------------- launch ----------------------------------------------------
extern "C" void kernel_launch(void* const* d_in, const int* in_sizes, int n_in,
                              void* d_out, int out_size, void* d_ws, size_t ws_size,
                              hipStream_t stream) {
  const float* tokens  = (const float*)d_in[0];
  const int*   pidx    = (const int*)d_in[1];
  const void*  pvraw   = (const void*)d_in[2];   // bool -> int32 on device (detected)
  const float* Wih_tok = (const float*)d_in[3];
  const float* Whh_tok = (const float*)d_in[4];
  const float* bih_tok = (const float*)d_in[5];
  const float* bhh_tok = (const float*)d_in[6];
  const float* Wih_ins = (const float*)d_in[7];
  const float* Whh_ins = (const float*)d_in[8];
  const float* bih_ins = (const float*)d_in[9];
  const float* bhh_ins = (const float*)d_in[10];
  const float* Wlin    = (const float*)d_in[11];
  const float* blin    = (const float*)d_in[12];

  char* ws = (char*)d_ws;
  const size_t OFF_XG   = 0;                        // 16384*1024*4 (one t-half, reused)
  const size_t OFF_H    = OFF_XG   + 67108864;
  const size_t OFF_C    = OFF_H    + 2097152;
  const size_t OFF_EMB  = OFF_C    + 2097152;
  const size_t OFF_WHH_H  = OFF_EMB   + 2097152;
  const size_t OFF_WHH_L  = OFF_WHH_H  + 524288;
  const size_t OFF_WIHI_H = OFF_WHH_L  + 524288;
  const size_t OFF_WIHI_L = OFF_WIHI_H + 524288;
  const size_t OFF_WHHI_H = OFF_WIHI_L + 524288;
  const size_t OFF_WHHI_L = OFF_WHHI_H + 524288;
  const size_t OFF_APP  = OFF_WHHI_L + 524288;
  const size_t OFF_PMX  = OFF_APP + 8192;
  const size_t OFF_PV8  = OFF_PMX + 32768;

  float*    Xg    = (float*)(ws + OFF_XG);
  float*    Hbuf  = (float*)(ws + OFF_H);
  float*    Cbuf  = (float*)(ws + OFF_C);
  float*    emb   = (float*)(ws + OFF_EMB);
  _Float16* WhhH  = (_Float16*)(ws + OFF_WHH_H);
  _Float16* WhhL  = (_Float16*)(ws + OFF_WHH_L);
  _Float16* WihIH = (_Float16*)(ws + OFF_WIHI_H);
  _Float16* WihIL = (_Float16*)(ws + OFF_WIHI_L);
  _Float16* WhhIH = (_Float16*)(ws + OFF_WHHI_H);
  _Float16* WhhIL = (_Float16*)(ws + OFF_WHHI_L);
  int*      app   = (int*)(ws + OFF_APP);
  float*    pmx   = (float*)(ws + OFF_PMX);
  unsigned char* pv8 = (unsigned char*)(ws + OFF_PV8);

  hipMemsetAsync(ws + OFF_APP, 0, 8192, stream);

  knorm<<<dim3(1), dim3(256), 0, stream>>>(pvraw, pv8);
  kw_cvt<<<dim3(1024), dim3(256), 0, stream>>>(Whh_tok, WhhH, WhhL,
                                               Wih_ins, WihIH, WihIL,
                                               Whh_ins, WhhIH, WhhIL);
  kapp<<<dim3(32), dim3(256), 0, stream>>>(pidx, pv8, app);
  // half 0: t = 0..7
  kg_gemm<<<dim3(1024), dim3(256), 0, stream>>>(tokens, Wih_tok, bih_tok, bhh_tok, Xg, 0);
  kr_rec<<<dim3(64), dim3(256), 0, stream>>>(Xg, WhhH, WhhL, Hbuf, Cbuf, emb, 0);
  // half 1: t = 8..15 (reuses Xg buffer)
  kg_gemm<<<dim3(1024), dim3(256), 0, stream>>>(tokens, Wih_tok, bih_tok, bhh_tok, Xg, 8);
  kr_rec<<<dim3(64), dim3(256), 0, stream>>>(Xg, WhhH, WhhL, Hbuf, Cbuf, emb, 1);
  // DAG: one kernel per level (stream order = cross-XCD visibility)
  for (int l = 0; l < NLVL; ++l) {
    klevel<<<dim3(32), dim3(256), 0, stream>>>(emb, WihIH, WihIL, WhhIH, WhhIL,
                                               bih_ins, bhh_ins, pidx, pv8,
                                               Hbuf, Cbuf, l);
  }
  kroot1<<<dim3(32), dim3(256), 0, stream>>>(Hbuf, app, pmx);
  kroot2<<<dim3(1), dim3(256), 0, stream>>>(pmx, Wlin, blin, (float*)d_out);
}

// Round 5
// 1209.204 us; speedup vs baseline: 1.3742x; 1.3455x over previous
//
#include <hip/hip_runtime.h>

// ---------------- problem constants ----------------
#define NTOK 2048   // instructions
#define TT   16     // tokens per instruction
#define EE   512    // token embed dim
#define HIDD 256    // hidden
#define G4   1024   // 4*HID gate dim
#define NLVL 16
#define KLVL 128    // instrs per level
#define INV2048 (1.0f/2048.0f)

typedef _Float16 v8h __attribute__((ext_vector_type(8)));
typedef _Float16 v4h __attribute__((ext_vector_type(4)));
typedef float    v4f __attribute__((ext_vector_type(4)));

__device__ __forceinline__ v4f mfma16(v8h a, v8h b, v4f c) {
  return __builtin_amdgcn_mfma_f32_16x16x32_f16(a, b, c, 0, 0, 0);
}

__device__ __forceinline__ float fsig(float x) {
  return 1.0f / (1.0f + __expf(-x));
}
__device__ __forceinline__ float ftanh(float x) {
  float ax = fabsf(x);
  float e  = __expf(-2.0f * ax);
  float t  = (1.0f - e) / (1.0f + e);
  return copysignf(t, x);
}

// split fp32 -> (hi fp16, lo fp16 scaled by 2048)
__device__ __forceinline__ void split8(const v4f& w0, const v4f& w1, v8h& hi, v8h& lo) {
#pragma unroll
  for (int u = 0; u < 4; ++u) {
    float v = w0[u]; _Float16 h = (_Float16)v;
    hi[u] = h; lo[u] = (_Float16)((v - (float)h) * 2048.0f);
  }
#pragma unroll
  for (int u = 0; u < 4; ++u) {
    float v = w1[u]; _Float16 h = (_Float16)v;
    hi[4+u] = h; lo[4+u] = (_Float16)((v - (float)h) * 2048.0f);
  }
}

// ---------------- K-1: normalize parent_valid to uchar[16384] ---------------
// Device encoding: int32 {0,1} (confirmed r3); detector kept (cheap, robust).
__global__ __launch_bounds__(256) void knorm(const void* __restrict__ pv_raw,
                                             unsigned char* __restrict__ pv8) {
  __shared__ int mode;   // 0 = int32, 1 = bytes, 2 = float32
  const int tid = threadIdx.x;
  if (tid == 0) mode = 0;
  __syncthreads();
  const unsigned* pu = (const unsigned*)pv_raw;
  int local = 0;
  for (int i = tid; i < 4096; i += 256) {
    unsigned v = pu[i];
    if (v == 0x3F800000u) { local = 2; break; }
    if (v > 1u) local = 1;
  }
  if (local) atomicMax(&mode, local);
  __syncthreads();
  const int m = mode;
  const unsigned char* pb = (const unsigned char*)pv_raw;
  const float* pf = (const float*)pv_raw;
  const int* pi = (const int*)pv_raw;
  for (int i = tid; i < NTOK * 8; i += 256) {
    unsigned char v;
    if (m == 1)      v = (pb[i] != 0);
    else if (m == 2) v = (pf[i] != 0.0f);
    else             v = (pi[i] != 0);
    pv8[i] = v;
  }
}

// ---------------- K0: weight splits -----------------------------------------
// blocks 0..1023: the 3 ins-LSTM [1024][256] matrices; blocks 1024..3071: Wih_tok [1024][512].
__global__ __launch_bounds__(256) void kw_cvt(
    const float* __restrict__ a0, _Float16* __restrict__ h0, _Float16* __restrict__ l0,
    const float* __restrict__ a1, _Float16* __restrict__ h1, _Float16* __restrict__ l1,
    const float* __restrict__ a2, _Float16* __restrict__ h2, _Float16* __restrict__ l2,
    const float* __restrict__ a3, _Float16* __restrict__ h3, _Float16* __restrict__ l3) {
  int i = blockIdx.x * 256 + threadIdx.x;
  if (blockIdx.x < 1024) {
    float v; _Float16 h;
    v = a0[i]; h = (_Float16)v; h0[i] = h; l0[i] = (_Float16)((v - (float)h) * 2048.0f);
    v = a1[i]; h = (_Float16)v; h1[i] = h; l1[i] = (_Float16)((v - (float)h) * 2048.0f);
    v = a2[i]; h = (_Float16)v; h2[i] = h; l2[i] = (_Float16)((v - (float)h) * 2048.0f);
  } else {
    int k = i - 262144;            // 0..524287
    float v = a3[k]; _Float16 h = (_Float16)v;
    h3[k] = h; l3[k] = (_Float16)((v - (float)h) * 2048.0f);
  }
}

// ---------------- K1: Xg = tokens @ Wih_tok^T (+biases), fp32, tiled layout --
// GEMM M-order: ar = t_local*2048 + instr  (t_local = ar>>11, instr = ar&2047)
// Xg store layout: Xg[((ar>>2)*G4 + col)*4 + (ar&3)]  -> v4f store/load per frag.
__global__ __launch_bounds__(256, 2) void kg_gemm(const float* __restrict__ A,
                                                  const _Float16* __restrict__ WtH,
                                                  const _Float16* __restrict__ WtL,
                                                  const float* __restrict__ b1,
                                                  const float* __restrict__ b2,
                                                  float* __restrict__ Xg, int t0) {
  __shared__ _Float16 AsH[128 * 72];
  __shared__ _Float16 AsL[128 * 72];
  __shared__ _Float16 BsH[128 * 72];
  __shared__ _Float16 BsL[128 * 72];
  const int tid  = threadIdx.x;
  const int lane = tid & 63;
  const int wv   = tid >> 6;
  const int wr   = (wv >> 1) * 64;
  const int wc   = (wv & 1) * 64;
  const int mb   = blockIdx.x >> 3;
  const int nb   = blockIdx.x & 7;
  const int row0 = mb * 128;      // ar base
  const int col0 = nb * 128;
  const int l15  = lane & 15;
  const int lq   = lane >> 4;
  const int tglob = (row0 >> 11) + t0;   // constant within block
  const int ib0   = row0 & 2047;         // instr base

  v4f acc1[4][4], acc2[4][4];
#pragma unroll
  for (int n = 0; n < 4; ++n) {
    int col  = col0 + wc + n * 16 + l15;
    float bb = b1[col] + b2[col];
#pragma unroll
    for (int m = 0; m < 4; ++m) { acc1[m][n] = (v4f){bb, bb, bb, bb}; acc2[m][n] = (v4f){0.f,0.f,0.f,0.f}; }
  }

#pragma unroll 1
  for (int kt = 0; kt < 8; ++kt) {
    const int k0 = kt * 64;
    // A: fp32 -> split in-register
#pragma unroll
    for (int i = 0; i < 8; ++i) {
      int chunk = tid + 256 * i;
      int r  = chunk >> 4;
      int c4 = (chunk & 15) * 4;
      int tokrow = (ib0 + r) * 16 + tglob;
      v4f av = *(const v4f*)(A + (size_t)tokrow * EE + k0 + c4);
      v4h ah, al;
#pragma unroll
      for (int u = 0; u < 4; ++u) {
        float v = av[u]; _Float16 h = (_Float16)v;
        ah[u] = h; al[u] = (_Float16)((v - (float)h) * 2048.0f);
      }
      *(v4h*)(AsH + r * 72 + c4) = ah;
      *(v4h*)(AsL + r * 72 + c4) = al;
    }
    // B: pre-split fp16, straight copy
#pragma unroll
    for (int i = 0; i < 4; ++i) {
      int chunk = tid + 256 * i;
      int r  = chunk >> 3;
      int c8 = (chunk & 7) * 8;
      *(v8h*)(BsH + r * 72 + c8) = *(const v8h*)(WtH + (size_t)(col0 + r) * EE + k0 + c8);
      *(v8h*)(BsL + r * 72 + c8) = *(const v8h*)(WtL + (size_t)(col0 + r) * EE + k0 + c8);
    }
    __syncthreads();
#pragma unroll
    for (int kk = 0; kk < 2; ++kk) {
      const int ko = kk * 32 + lq * 8;
      v8h afh[4], afl[4], bfh[4], bfl[4];
#pragma unroll
      for (int m = 0; m < 4; ++m) {
        afh[m] = *(const v8h*)(AsH + (wr + m * 16 + l15) * 72 + ko);
        afl[m] = *(const v8h*)(AsL + (wr + m * 16 + l15) * 72 + ko);
      }
#pragma unroll
      for (int n = 0; n < 4; ++n) {
        bfh[n] = *(const v8h*)(BsH + (wc + n * 16 + l15) * 72 + ko);
        bfl[n] = *(const v8h*)(BsL + (wc + n * 16 + l15) * 72 + ko);
      }
#pragma unroll
      for (int m = 0; m < 4; ++m)
#pragma unroll
        for (int n = 0; n < 4; ++n) {
          acc1[m][n] = mfma16(afh[m], bfh[n], acc1[m][n]);
          acc2[m][n] = mfma16(afl[m], bfh[n], acc2[m][n]);
          acc2[m][n] = mfma16(afh[m], bfl[n], acc2[m][n]);
        }
    }
    __syncthreads();
  }

#pragma unroll
  for (int m = 0; m < 4; ++m)
#pragma unroll
    for (int n = 0; n < 4; ++n) {
      int row = row0 + wr + m * 16 + lq * 4;     // ar, multiple of 4
      int col = col0 + wc + n * 16 + l15;
      v4f o;
#pragma unroll
      for (int r = 0; r < 4; ++r) o[r] = acc1[m][n][r] + acc2[m][n][r] * INV2048;
      *(v4f*)(Xg + ((size_t)(row >> 2) * G4 + col) * 4) = o;
    }
}

// ---------------- K2: token LSTM recurrence, 8 steps per half ---------------
// 128 blocks x 16 rows x 4 waves. Xg v4f loads as MFMA C-init (latency hidden).
__global__ __launch_bounds__(256, 1) void kr_rec(const float* __restrict__ Xg,
                                                 const _Float16* __restrict__ WhhH,
                                                 const _Float16* __restrict__ WhhL,
                                                 float* __restrict__ Hst,
                                                 float* __restrict__ Cst,
                                                 float* __restrict__ emb, int half) {
  __shared__ float hbuf[16 * 260];
  const int tid  = threadIdx.x;
  const int lane = tid & 63;
  const int wv   = tid >> 6;
  const int l15  = lane & 15;
  const int lq   = lane >> 4;
  const int r0   = blockIdx.x * 16;

  v4f c[4];
  if (half) {
#pragma unroll
    for (int j = 0; j < 4; ++j) {
      const int feat = 16 * (wv + 4 * j) + l15;
#pragma unroll
      for (int r = 0; r < 4; ++r)
        c[j][r] = Cst[(size_t)(r0 + lq * 4 + r) * HIDD + feat];
    }
#pragma unroll
    for (int it = 0; it < 16; ++it) {
      int idx = it * 256 + tid;
      hbuf[(idx >> 8) * 260 + (idx & 255)] = Hst[(size_t)(r0 + (idx >> 8)) * HIDD + (idx & 255)];
    }
  } else {
#pragma unroll
    for (int j = 0; j < 4; ++j) c[j] = (v4f){0.f, 0.f, 0.f, 0.f};
  }
  __syncthreads();

#pragma unroll 1
  for (int tl = 0; tl < 8; ++tl) {
    const bool have_h = half || (tl > 0);
    v4f acc1[4][4], acc2[4][4];
    // acc1 init = Xg fragment loads (independent of recurrence -> issued early)
    const size_t xrow = (size_t)(tl * 512 + (r0 >> 2) + lq) * G4;
#pragma unroll
    for (int g = 0; g < 4; ++g)
#pragma unroll
      for (int j = 0; j < 4; ++j) {
        const int col = 256 * g + 16 * (wv + 4 * j) + l15;
        acc1[g][j] = *(const v4f*)(Xg + (xrow + col) * 4);
        acc2[g][j] = (v4f){0.f, 0.f, 0.f, 0.f};
      }
    if (have_h) {
#pragma unroll 1
      for (int kk = 0; kk < 8; ++kk) {
        const int ko = kk * 32 + lq * 8;
        v4f w0 = *(const v4f*)(hbuf + l15 * 260 + ko);
        v4f w1 = *(const v4f*)(hbuf + l15 * 260 + ko + 4);
        v8h ah, al;
        split8(w0, w1, ah, al);
#pragma unroll
        for (int g = 0; g < 4; ++g)
#pragma unroll
          for (int j = 0; j < 4; ++j) {
            const int fc = 16 * g + wv + 4 * j;
            v8h bh = *(const v8h*)(WhhH + (size_t)(16 * fc + l15) * HIDD + ko);
            v8h bl = *(const v8h*)(WhhL + (size_t)(16 * fc + l15) * HIDD + ko);
            acc1[g][j] = mfma16(ah, bh, acc1[g][j]);
            acc2[g][j] = mfma16(al, bh, acc2[g][j]);
            acc2[g][j] = mfma16(ah, bl, acc2[g][j]);
          }
      }
    }
    __syncthreads();   // all hbuf reads done before overwrite
#pragma unroll
    for (int j = 0; j < 4; ++j) {
      const int feat = 16 * (wv + 4 * j) + l15;
#pragma unroll
      for (int r = 0; r < 4; ++r) {
        const int rr = lq * 4 + r;
        float ig = acc1[0][j][r] + acc2[0][j][r] * INV2048;
        float fg = acc1[1][j][r] + acc2[1][j][r] * INV2048;
        float gg = acc1[2][j][r] + acc2[2][j][r] * INV2048;
        float og = acc1[3][j][r] + acc2[3][j][r] * INV2048;
        float cn = fsig(fg) * c[j][r] + fsig(ig) * ftanh(gg);
        float hn = fsig(og) * ftanh(cn);
        c[j][r] = cn;
        hbuf[rr * 260 + feat] = hn;
        if (tl == 7) {
          const size_t grow = r0 + rr;
          if (!half) { Hst[grow * HIDD + feat] = hn; Cst[grow * HIDD + feat] = cn; }
          else       { emb[grow * HIDD + feat] = hn; }
        }
      }
    }
    __syncthreads();   // writes visible before next step's reads
  }
}

// ---------------- K3a: appears scatter (32 blocks) --------------------------
__global__ __launch_bounds__(256) void kapp(const int* __restrict__ pidx,
                                            const unsigned char* __restrict__ pval,
                                            int* __restrict__ appears) {
  int e = blockIdx.x * 512 + threadIdx.x * 2;
#pragma unroll
  for (int u = 0; u < 2; ++u, ++e) {
    if (pval[e]) atomicAdd(appears + pidx[e], 1);
  }
}

// ---------------- K3b: one DAG level (32 blocks) ----------------------------
__global__ __launch_bounds__(256) void klevel(
    const float* __restrict__ emb,
    const _Float16* __restrict__ WihH, const _Float16* __restrict__ WihL,
    const _Float16* __restrict__ WhhH, const _Float16* __restrict__ WhhL,
    const float* __restrict__ bi, const float* __restrict__ bh,
    const int* __restrict__ pidx, const unsigned char* __restrict__ pval,
    float* __restrict__ H, float* __restrict__ C, int l) {
  __shared__ float h0s[16 * 260];
  __shared__ float c0s[16 * 260];
  __shared__ int      pis[128];
  __shared__ unsigned char pvs[128];
  const int tid  = threadIdx.x;
  const int lane = tid & 63;
  const int wv   = tid >> 6;
  const int l15  = lane & 15;
  const int lq   = lane >> 4;
  const int b    = blockIdx.x;
  const int mf   = b >> 2;
  const int q    = b & 3;
  const int fi   = q * 4 + wv;

  if (tid < 128) {
    int rr = tid >> 3, p = tid & 7;
    int row = l * KLVL + mf * 16 + rr;
    pis[tid] = pidx[row * 8 + p];
    pvs[tid] = pval[row * 8 + p];
  }
  __syncthreads();
#pragma unroll 1
  for (int it = 0; it < 4; ++it) {
    int task = tid + 256 * it;
    int rr = task >> 6;
    int f4 = (task & 63) * 4;
    v4f hm = (v4f){-1e30f, -1e30f, -1e30f, -1e30f};
    v4f cm = hm;
    bool any = false;
#pragma unroll
    for (int p = 0; p < 8; ++p) {
      if (pvs[rr * 8 + p]) {
        any = true;
        int par = pis[rr * 8 + p];
        v4f hv = *(const v4f*)(H + (size_t)par * HIDD + f4);
        v4f cv = *(const v4f*)(C + (size_t)par * HIDD + f4);
#pragma unroll
        for (int u = 0; u < 4; ++u) { hm[u] = fmaxf(hm[u], hv[u]); cm[u] = fmaxf(cm[u], cv[u]); }
      }
    }
    if (!any) { hm = (v4f){0.f,0.f,0.f,0.f}; cm = (v4f){0.f,0.f,0.f,0.f}; }
    *(v4f*)(h0s + rr * 260 + f4) = hm;
    *(v4f*)(c0s + rr * 260 + f4) = cm;
  }
  __syncthreads();

  v4f acc1[4], acc2[4];
#pragma unroll
  for (int g = 0; g < 4; ++g) {
    int col  = 256 * g + 16 * fi + l15;
    float bb = bi[col] + bh[col];
    acc1[g] = (v4f){bb, bb, bb, bb};
    acc2[g] = (v4f){0.f, 0.f, 0.f, 0.f};
  }
  const int arow = l * KLVL + mf * 16 + l15;
#pragma unroll 1
  for (int kk = 0; kk < 8; ++kk) {   // x @ Wih^T
    const int ko = kk * 32 + lq * 8;
    v4f x0 = *(const v4f*)(emb + (size_t)arow * HIDD + ko);
    v4f x1 = *(const v4f*)(emb + (size_t)arow * HIDD + ko + 4);
    v8h axh, axl;
    split8(x0, x1, axh, axl);
#pragma unroll
    for (int g = 0; g < 4; ++g) {
      int n = 256 * g + 16 * fi + l15;
      v8h bh8 = *(const v8h*)(WihH + (size_t)n * HIDD + ko);
      v8h bl8 = *(const v8h*)(WihL + (size_t)n * HIDD + ko);
      acc1[g] = mfma16(axh, bh8, acc1[g]);
      acc2[g] = mfma16(axl, bh8, acc2[g]);
      acc2[g] = mfma16(axh, bl8, acc2[g]);
    }
  }
#pragma unroll 1
  for (int kk = 0; kk < 8; ++kk) {   // h0 @ Whh^T
    const int ko = kk * 32 + lq * 8;
    v4f h0 = *(const v4f*)(h0s + l15 * 260 + ko);
    v4f h1 = *(const v4f*)(h0s + l15 * 260 + ko + 4);
    v8h ahh, ahl;
    split8(h0, h1, ahh, ahl);
#pragma unroll
    for (int g = 0; g < 4; ++g) {
      int n = 256 * g + 16 * fi + l15;
      v8h bh8 = *(const v8h*)(WhhH + (size_t)n * HIDD + ko);
      v8h bl8 = *(const v8h*)(WhhL + (size_t)n * HIDD + ko);
      acc1[g] = mfma16(ahh, bh8, acc1[g]);
      acc2[g] = mfma16(ahl, bh8, acc2[g]);
      acc2[g] = mfma16(ahh, bl8, acc2[g]);
    }
  }
#pragma unroll
  for (int r = 0; r < 4; ++r) {
    int rr = lq * 4 + r;
    int n  = 16 * fi + l15;
    float ig = acc1[0][r] + acc2[0][r] * INV2048;
    float fg = acc1[1][r] + acc2[1][r] * INV2048;
    float gg = acc1[2][r] + acc2[2][r] * INV2048;
    float og = acc1[3][r] + acc2[3][r] * INV2048;
    float c0 = c0s[rr * 260 + n];
    float cn = fsig(fg) * c0 + fsig(ig) * ftanh(gg);
    float hn = fsig(og) * ftanh(cn);
    int grow = l * KLVL + mf * 16 + rr;
    H[(size_t)grow * HIDD + n] = hn;
    C[(size_t)grow * HIDD + n] = cn;
  }
}

// ---------------- K4a: partial root max (32 blocks x 64 rows) ---------------
__global__ __launch_bounds__(256) void kroot1(const float* __restrict__ H,
                                              const int* __restrict__ appears,
                                              float* __restrict__ pmax) {
  __shared__ int app[64];
  const int tid = threadIdx.x;
  const int rb  = blockIdx.x * 64;
  if (tid < 64) app[tid] = appears[rb + tid];
  __syncthreads();
  float m = -1e30f;
#pragma unroll 1
  for (int r = 0; r < 64; ++r) {
    if (app[r] == 0) m = fmaxf(m, H[(size_t)(rb + r) * HIDD + tid]);
  }
  pmax[blockIdx.x * 256 + tid] = m;
}

// ---------------- K4b: final combine + linear -------------------------------
__global__ __launch_bounds__(256) void kroot2(const float* __restrict__ pmax,
                                              const float* __restrict__ Wlin,
                                              const float* __restrict__ blin,
                                              float* __restrict__ out) {
  __shared__ float red[256];
  const int tid = threadIdx.x;
  float m = pmax[tid];
#pragma unroll 1
  for (int bb = 1; bb < 32; ++bb) m = fmaxf(m, pmax[bb * 256 + tid]);
  red[tid] = m * Wlin[tid];
  __syncthreads();
  if (tid == 0) {
    float s = 0.f;
    for (int i2 = 0; i2 < 256; ++i2) s += red[i2];
    out[0] = s + blin[0];
  }
}

// ---------------- launch ----------------------------------------------------
extern "C" void kernel_launch(void* const* d_in, const int* in_sizes, int n_in,
                              void* d_out, int out_size, void* d_ws, size_t ws_size,
                              hipStream_t stream) {
  const float* tokens  = (const float*)d_in[0];
  const int*   pidx    = (const int*)d_in[1];
  const void*  pvraw   = (const void*)d_in[2];
  const float* Wih_tok = (const float*)d_in[3];
  const float* Whh_tok = (const float*)d_in[4];
  const float* bih_tok = (const float*)d_in[5];
  const float* bhh_tok = (const float*)d_in[6];
  const float* Wih_ins = (const float*)d_in[7];
  const float* Whh_ins = (const float*)d_in[8];
  const float* bih_ins = (const float*)d_in[9];
  const float* bhh_ins = (const float*)d_in[10];
  const float* Wlin    = (const float*)d_in[11];
  const float* blin    = (const float*)d_in[12];

  char* ws = (char*)d_ws;
  const size_t OFF_XG   = 0;                        // 16384*1024*4 (one t-half, reused)
  const size_t OFF_H    = OFF_XG   + 67108864;
  const size_t OFF_C    = OFF_H    + 2097152;
  const size_t OFF_EMB  = OFF_C    + 2097152;
  const size_t OFF_WHH_H  = OFF_EMB   + 2097152;
  const size_t OFF_WHH_L  = OFF_WHH_H  + 524288;
  const size_t OFF_WIHI_H = OFF_WHH_L  + 524288;
  const size_t OFF_WIHI_L = OFF_WIHI_H + 524288;
  const size_t OFF_WHHI_H = OFF_WIHI_L + 524288;
  const size_t OFF_WHHI_L = OFF_WHHI_H + 524288;
  const size_t OFF_WT_H   = OFF_WHHI_L + 524288;    // 1024*512*2 = 1048576
  const size_t OFF_WT_L   = OFF_WT_H   + 1048576;
  const size_t OFF_APP  = OFF_WT_L + 1048576;
  const size_t OFF_PMX  = OFF_APP + 8192;
  const size_t OFF_PV8  = OFF_PMX + 32768;

  float*    Xg    = (float*)(ws + OFF_XG);
  float*    Hbuf  = (float*)(ws + OFF_H);
  float*    Cbuf  = (float*)(ws + OFF_C);
  float*    emb   = (float*)(ws + OFF_EMB);
  _Float16* WhhH  = (_Float16*)(ws + OFF_WHH_H);
  _Float16* WhhL  = (_Float16*)(ws + OFF_WHH_L);
  _Float16* WihIH = (_Float16*)(ws + OFF_WIHI_H);
  _Float16* WihIL = (_Float16*)(ws + OFF_WIHI_L);
  _Float16* WhhIH = (_Float16*)(ws + OFF_WHHI_H);
  _Float16* WhhIL = (_Float16*)(ws + OFF_WHHI_L);
  _Float16* WtH   = (_Float16*)(ws + OFF_WT_H);
  _Float16* WtL   = (_Float16*)(ws + OFF_WT_L);
  int*      app   = (int*)(ws + OFF_APP);
  float*    pmx   = (float*)(ws + OFF_PMX);
  unsigned char* pv8 = (unsigned char*)(ws + OFF_PV8);

  hipMemsetAsync(ws + OFF_APP, 0, 8192, stream);

  knorm<<<dim3(1), dim3(256), 0, stream>>>(pvraw, pv8);
  kw_cvt<<<dim3(3072), dim3(256), 0, stream>>>(Whh_tok, WhhH, WhhL,
                                               Wih_ins, WihIH, WihIL,
                                               Whh_ins, WhhIH, WhhIL,
                                               Wih_tok, WtH, WtL);
  kapp<<<dim3(32), dim3(256), 0, stream>>>(pidx, pv8, app);
  // half 0: t = 0..7
  kg_gemm<<<dim3(1024), dim3(256), 0, stream>>>(tokens, WtH, WtL, bih_tok, bhh_tok, Xg, 0);
  kr_rec<<<dim3(128), dim3(256), 0, stream>>>(Xg, WhhH, WhhL, Hbuf, Cbuf, emb, 0);
  // half 1: t = 8..15 (reuses Xg buffer)
  kg_gemm<<<dim3(1024), dim3(256), 0, stream>>>(tokens, WtH, WtL, bih_tok, bhh_tok, Xg, 8);
  kr_rec<<<dim3(128), dim3(256), 0, stream>>>(Xg, WhhH, WhhL, Hbuf, Cbuf, emb, 1);
  // DAG: one kernel per level
  for (int l = 0; l < NLVL; ++l) {
    klevel<<<dim3(32), dim3(256), 0, stream>>>(emb, WihIH, WihIL, WhhIH, WhhIL,
                                               bih_ins, bhh_ins, pidx, pv8,
                                               Hbuf, Cbuf, l);
  }
  kroot1<<<dim3(32), dim3(256), 0, stream>>>(Hbuf, app, pmx);
  kroot2<<<dim3(1), dim3(256), 0, stream>>>(pmx, Wlin, blin, (float*)d_out);
}

// Round 6
// 1171.069 us; speedup vs baseline: 1.4190x; 1.0326x over previous
//
#include <hip/hip_runtime.h>

// ---------------- problem constants ----------------
#define NTOK 2048   // instructions
#define TT   16     // tokens per instruction
#define EE   512    // token embed dim
#define HIDD 256    // hidden
#define G4   1024   // 4*HID gate dim
#define NLVL 16
#define KLVL 128    // instrs per level
#define INV2048 (1.0f/2048.0f)

typedef _Float16 v8h __attribute__((ext_vector_type(8)));
typedef _Float16 v4h __attribute__((ext_vector_type(4)));
typedef float    v4f __attribute__((ext_vector_type(4)));

__device__ __forceinline__ v4f mfma16(v8h a, v8h b, v4f c) {
  return __builtin_amdgcn_mfma_f32_16x16x32_f16(a, b, c, 0, 0, 0);
}

__device__ __forceinline__ float fsig(float x) {
  return 1.0f / (1.0f + __expf(-x));
}
__device__ __forceinline__ float ftanh(float x) {
  float ax = fabsf(x);
  float e  = __expf(-2.0f * ax);
  float t  = (1.0f - e) / (1.0f + e);
  return copysignf(t, x);
}

// split fp32 -> (hi fp16, lo fp16 scaled by 2048)
__device__ __forceinline__ void split8(const v4f& w0, const v4f& w1, v8h& hi, v8h& lo) {
#pragma unroll
  for (int u = 0; u < 4; ++u) {
    float v = w0[u]; _Float16 h = (_Float16)v;
    hi[u] = h; lo[u] = (_Float16)((v - (float)h) * 2048.0f);
  }
#pragma unroll
  for (int u = 0; u < 4; ++u) {
    float v = w1[u]; _Float16 h = (_Float16)v;
    hi[4+u] = h; lo[4+u] = (_Float16)((v - (float)h) * 2048.0f);
  }
}

// ---------------- K-1: normalize parent_valid to uchar[16384] ---------------
__global__ __launch_bounds__(256) void knorm(const void* __restrict__ pv_raw,
                                             unsigned char* __restrict__ pv8) {
  __shared__ int mode;   // 0 = int32, 1 = bytes, 2 = float32
  const int tid = threadIdx.x;
  if (tid == 0) mode = 0;
  __syncthreads();
  const unsigned* pu = (const unsigned*)pv_raw;
  int local = 0;
  for (int i = tid; i < 4096; i += 256) {
    unsigned v = pu[i];
    if (v == 0x3F800000u) { local = 2; break; }
    if (v > 1u) local = 1;
  }
  if (local) atomicMax(&mode, local);
  __syncthreads();
  const int m = mode;
  const unsigned char* pb = (const unsigned char*)pv_raw;
  const float* pf = (const float*)pv_raw;
  const int* pi = (const int*)pv_raw;
  for (int i = tid; i < NTOK * 8; i += 256) {
    unsigned char v;
    if (m == 1)      v = (pb[i] != 0);
    else if (m == 2) v = (pf[i] != 0.0f);
    else             v = (pi[i] != 0);
    pv8[i] = v;
  }
}

// ---------------- K0: weight splits -----------------------------------------
// blocks 0..1023: Whh_tok -> whh2 interleaved [row][chunk][{hi8,lo8}],
//                 Wih_ins/Whh_ins -> flat hi/lo pairs;
// blocks 1024..3071: Wih_tok [1024][512] -> WtH/WtL flat.
__global__ __launch_bounds__(256) void kw_cvt(
    const float* __restrict__ a0, _Float16* __restrict__ whh2,
    const float* __restrict__ a1, _Float16* __restrict__ h1, _Float16* __restrict__ l1,
    const float* __restrict__ a2, _Float16* __restrict__ h2, _Float16* __restrict__ l2,
    const float* __restrict__ a3, _Float16* __restrict__ h3, _Float16* __restrict__ l3) {
  int i = blockIdx.x * 256 + threadIdx.x;
  if (blockIdx.x < 1024) {
    float v; _Float16 h;
    // a0: Whh_tok [1024][256] -> interleaved hi/lo 8-chunks
    {
      int row = i >> 8, col = i & 255;
      int base = row * 512 + ((col >> 3) << 4) + (col & 7);
      v = a0[i]; h = (_Float16)v;
      whh2[base]     = h;
      whh2[base + 8] = (_Float16)((v - (float)h) * 2048.0f);
    }
    v = a1[i]; h = (_Float16)v; h1[i] = h; l1[i] = (_Float16)((v - (float)h) * 2048.0f);
    v = a2[i]; h = (_Float16)v; h2[i] = h; l2[i] = (_Float16)((v - (float)h) * 2048.0f);
  } else {
    int k = i - 262144;            // 0..524287
    float v = a3[k]; _Float16 h = (_Float16)v;
    h3[k] = h; l3[k] = (_Float16)((v - (float)h) * 2048.0f);
  }
}

// ---------------- K1: Xg = tokens @ Wih_tok^T (+biases), fp32, tiled layout --
// GEMM M-order: ar = t_local*2048 + instr; store Xg[((ar>>2)*G4 + col)*4 + (ar&3)].
__global__ __launch_bounds__(256, 2) void kg_gemm(const float* __restrict__ A,
                                                  const _Float16* __restrict__ WtH,
                                                  const _Float16* __restrict__ WtL,
                                                  const float* __restrict__ b1,
                                                  const float* __restrict__ b2,
                                                  float* __restrict__ Xg, int t0) {
  __shared__ _Float16 AsH[128 * 72];
  __shared__ _Float16 AsL[128 * 72];
  __shared__ _Float16 BsH[128 * 72];
  __shared__ _Float16 BsL[128 * 72];
  const int tid  = threadIdx.x;
  const int lane = tid & 63;
  const int wv   = tid >> 6;
  const int wr   = (wv >> 1) * 64;
  const int wc   = (wv & 1) * 64;
  const int mb   = blockIdx.x >> 3;
  const int nb   = blockIdx.x & 7;
  const int row0 = mb * 128;
  const int col0 = nb * 128;
  const int l15  = lane & 15;
  const int lq   = lane >> 4;
  const int tglob = (row0 >> 11) + t0;
  const int ib0   = row0 & 2047;

  v4f acc1[4][4], acc2[4][4];
#pragma unroll
  for (int n = 0; n < 4; ++n) {
    int col  = col0 + wc + n * 16 + l15;
    float bb = b1[col] + b2[col];
#pragma unroll
    for (int m = 0; m < 4; ++m) { acc1[m][n] = (v4f){bb, bb, bb, bb}; acc2[m][n] = (v4f){0.f,0.f,0.f,0.f}; }
  }

#pragma unroll 1
  for (int kt = 0; kt < 8; ++kt) {
    const int k0 = kt * 64;
#pragma unroll
    for (int i = 0; i < 8; ++i) {
      int chunk = tid + 256 * i;
      int r  = chunk >> 4;
      int c4 = (chunk & 15) * 4;
      int tokrow = (ib0 + r) * 16 + tglob;
      v4f av = *(const v4f*)(A + (size_t)tokrow * EE + k0 + c4);
      v4h ah, al;
#pragma unroll
      for (int u = 0; u < 4; ++u) {
        float v = av[u]; _Float16 h = (_Float16)v;
        ah[u] = h; al[u] = (_Float16)((v - (float)h) * 2048.0f);
      }
      *(v4h*)(AsH + r * 72 + c4) = ah;
      *(v4h*)(AsL + r * 72 + c4) = al;
    }
#pragma unroll
    for (int i = 0; i < 4; ++i) {
      int chunk = tid + 256 * i;
      int r  = chunk >> 3;
      int c8 = (chunk & 7) * 8;
      *(v8h*)(BsH + r * 72 + c8) = *(const v8h*)(WtH + (size_t)(col0 + r) * EE + k0 + c8);
      *(v8h*)(BsL + r * 72 + c8) = *(const v8h*)(WtL + (size_t)(col0 + r) * EE + k0 + c8);
    }
    __syncthreads();
#pragma unroll
    for (int kk = 0; kk < 2; ++kk) {
      const int ko = kk * 32 + lq * 8;
      v8h afh[4], afl[4], bfh[4], bfl[4];
#pragma unroll
      for (int m = 0; m < 4; ++m) {
        afh[m] = *(const v8h*)(AsH + (wr + m * 16 + l15) * 72 + ko);
        afl[m] = *(const v8h*)(AsL + (wr + m * 16 + l15) * 72 + ko);
      }
#pragma unroll
      for (int n = 0; n < 4; ++n) {
        bfh[n] = *(const v8h*)(BsH + (wc + n * 16 + l15) * 72 + ko);
        bfl[n] = *(const v8h*)(BsL + (wc + n * 16 + l15) * 72 + ko);
      }
#pragma unroll
      for (int m = 0; m < 4; ++m)
#pragma unroll
        for (int n = 0; n < 4; ++n) {
          acc1[m][n] = mfma16(afh[m], bfh[n], acc1[m][n]);
          acc2[m][n] = mfma16(afl[m], bfh[n], acc2[m][n]);
          acc2[m][n] = mfma16(afh[m], bfl[n], acc2[m][n]);
        }
    }
    __syncthreads();
  }

#pragma unroll
  for (int m = 0; m < 4; ++m)
#pragma unroll
    for (int n = 0; n < 4; ++n) {
      int row = row0 + wr + m * 16 + lq * 4;
      int col = col0 + wc + n * 16 + l15;
      v4f o;
#pragma unroll
      for (int r = 0; r < 4; ++r) o[r] = acc1[m][n][r] + acc2[m][n][r] * INV2048;
      *(v4f*)(Xg + ((size_t)(row >> 2) * G4 + col) * 4) = o;
    }
}

// ---------------- K2: token LSTM recurrence, 8 steps per half ---------------
// 128 blocks x 16 rows x 8 waves. Waves split kk: w>>2==0 -> kk 0..3 (+Xg init,
// gates, c, hbuf); w>>2==1 -> kk 4..7, partial sums reduced through LDS.
__global__ __launch_bounds__(512, 2) void kr_rec(const float* __restrict__ Xg,
                                                 const _Float16* __restrict__ Whh2,
                                                 float* __restrict__ Hst,
                                                 float* __restrict__ Cst,
                                                 float* __restrict__ emb, int half) {
  __shared__ float hbuf[16 * 260];
  __shared__ v4f red[4][16][64];   // [wv][g*4+j][lane] : 64 KB
  const int tid  = threadIdx.x;
  const int lane = tid & 63;
  const int w    = tid >> 6;       // 0..7
  const int wv   = w & 3;
  const int kkh  = w >> 2;         // 0: kk 0-3, 1: kk 4-7
  const int l15  = lane & 15;
  const int lq   = lane >> 4;
  const int r0   = blockIdx.x * 16;

  v4f c[4];
  if (kkh == 0) {
    if (half) {
#pragma unroll
      for (int j = 0; j < 4; ++j) {
        const int feat = 16 * (wv + 4 * j) + l15;
#pragma unroll
        for (int r = 0; r < 4; ++r)
          c[j][r] = Cst[(size_t)(r0 + lq * 4 + r) * HIDD + feat];
      }
    } else {
#pragma unroll
      for (int j = 0; j < 4; ++j) c[j] = (v4f){0.f, 0.f, 0.f, 0.f};
    }
  }
  if (half) {
    for (int idx = tid; idx < 4096; idx += 512)
      hbuf[(idx >> 8) * 260 + (idx & 255)] = Hst[(size_t)(r0 + (idx >> 8)) * HIDD + (idx & 255)];
  }
  __syncthreads();

#pragma unroll 1
  for (int tl = 0; tl < 8; ++tl) {
    const bool have_h = half || (tl > 0);
    v4f acc1[4][4], acc2[4][4];
    if (kkh == 0) {
      const size_t xrow = (size_t)(tl * 512 + (r0 >> 2) + lq) * G4;
#pragma unroll
      for (int g = 0; g < 4; ++g)
#pragma unroll
        for (int j = 0; j < 4; ++j) {
          const int col = 256 * g + 16 * (wv + 4 * j) + l15;
          acc1[g][j] = *(const v4f*)(Xg + (xrow + col) * 4);
          acc2[g][j] = (v4f){0.f, 0.f, 0.f, 0.f};
        }
    } else {
#pragma unroll
      for (int g = 0; g < 4; ++g)
#pragma unroll
        for (int j = 0; j < 4; ++j) {
          acc1[g][j] = (v4f){0.f, 0.f, 0.f, 0.f};
          acc2[g][j] = (v4f){0.f, 0.f, 0.f, 0.f};
        }
    }
    if (have_h) {
#pragma unroll 1
      for (int kk2 = 0; kk2 < 4; ++kk2) {
        const int ko = (kkh * 4 + kk2) * 32 + lq * 8;
        v4f w0 = *(const v4f*)(hbuf + l15 * 260 + ko);
        v4f w1 = *(const v4f*)(hbuf + l15 * 260 + ko + 4);
        v8h ah, al;
        split8(w0, w1, ah, al);
        const int ch16 = (ko >> 3) << 4;   // interleaved chunk byte-offset (halves)
#pragma unroll
        for (int g = 0; g < 4; ++g)
#pragma unroll
          for (int j = 0; j < 4; ++j) {
            const int fc = 16 * g + wv + 4 * j;
            const _Float16* p = Whh2 + (size_t)(16 * fc + l15) * 512 + ch16;
            v8h bh = *(const v8h*)p;
            v8h bl = *(const v8h*)(p + 8);
            acc1[g][j] = mfma16(ah, bh, acc1[g][j]);
            acc2[g][j] = mfma16(al, bh, acc2[g][j]);
            acc2[g][j] = mfma16(ah, bl, acc2[g][j]);
          }
      }
    }
    if (kkh == 1) {
#pragma unroll
      for (int g = 0; g < 4; ++g)
#pragma unroll
        for (int j = 0; j < 4; ++j)
          red[wv][g * 4 + j][lane] = acc1[g][j] + acc2[g][j] * INV2048;
    }
    __syncthreads();   // red written; all hbuf reads complete
    if (kkh == 0) {
#pragma unroll
      for (int j = 0; j < 4; ++j) {
        const int feat = 16 * (wv + 4 * j) + l15;
        v4f si = acc1[0][j] + acc2[0][j] * INV2048 + red[wv][0 * 4 + j][lane];
        v4f sf = acc1[1][j] + acc2[1][j] * INV2048 + red[wv][1 * 4 + j][lane];
        v4f sg = acc1[2][j] + acc2[2][j] * INV2048 + red[wv][2 * 4 + j][lane];
        v4f so = acc1[3][j] + acc2[3][j] * INV2048 + red[wv][3 * 4 + j][lane];
#pragma unroll
        for (int r = 0; r < 4; ++r) {
          const int rr = lq * 4 + r;
          float cn = fsig(sf[r]) * c[j][r] + fsig(si[r]) * ftanh(sg[r]);
          float hn = fsig(so[r]) * ftanh(cn);
          c[j][r] = cn;
          hbuf[rr * 260 + feat] = hn;
          if (tl == 7) {
            const size_t grow = r0 + rr;
            if (!half) { Hst[grow * HIDD + feat] = hn; Cst[grow * HIDD + feat] = cn; }
            else       { emb[grow * HIDD + feat] = hn; }
          }
        }
      }
    }
    __syncthreads();   // hbuf writes visible before next step's reads
  }
}

// ---------------- K3a: appears scatter (32 blocks) --------------------------
__global__ __launch_bounds__(256) void kapp(const int* __restrict__ pidx,
                                            const unsigned char* __restrict__ pval,
                                            int* __restrict__ appears) {
  int e = blockIdx.x * 512 + threadIdx.x * 2;
#pragma unroll
  for (int u = 0; u < 2; ++u, ++e) {
    if (pval[e]) atomicAdd(appears + pidx[e], 1);
  }
}

// ---------------- K3b: one DAG level (32 blocks) ----------------------------
__global__ __launch_bounds__(256) void klevel(
    const float* __restrict__ emb,
    const _Float16* __restrict__ WihH, const _Float16* __restrict__ WihL,
    const _Float16* __restrict__ WhhH, const _Float16* __restrict__ WhhL,
    const float* __restrict__ bi, const float* __restrict__ bh,
    const int* __restrict__ pidx, const unsigned char* __restrict__ pval,
    float* __restrict__ H, float* __restrict__ C, int l) {
  __shared__ float h0s[16 * 260];
  __shared__ float c0s[16 * 260];
  __shared__ int      pis[128];
  __shared__ unsigned char pvs[128];
  const int tid  = threadIdx.x;
  const int lane = tid & 63;
  const int wv   = tid >> 6;
  const int l15  = lane & 15;
  const int lq   = lane >> 4;
  const int b    = blockIdx.x;
  const int mf   = b >> 2;
  const int q    = b & 3;
  const int fi   = q * 4 + wv;

  if (tid < 128) {
    int rr = tid >> 3, p = tid & 7;
    int row = l * KLVL + mf * 16 + rr;
    pis[tid] = pidx[row * 8 + p];
    pvs[tid] = pval[row * 8 + p];
  }
  __syncthreads();
#pragma unroll 1
  for (int it = 0; it < 4; ++it) {
    int task = tid + 256 * it;
    int rr = task >> 6;
    int f4 = (task & 63) * 4;
    v4f hm = (v4f){-1e30f, -1e30f, -1e30f, -1e30f};
    v4f cm = hm;
    bool any = false;
#pragma unroll
    for (int p = 0; p < 8; ++p) {
      if (pvs[rr * 8 + p]) {
        any = true;
        int par = pis[rr * 8 + p];
        v4f hv = *(const v4f*)(H + (size_t)par * HIDD + f4);
        v4f cv = *(const v4f*)(C + (size_t)par * HIDD + f4);
#pragma unroll
        for (int u = 0; u < 4; ++u) { hm[u] = fmaxf(hm[u], hv[u]); cm[u] = fmaxf(cm[u], cv[u]); }
      }
    }
    if (!any) { hm = (v4f){0.f,0.f,0.f,0.f}; cm = (v4f){0.f,0.f,0.f,0.f}; }
    *(v4f*)(h0s + rr * 260 + f4) = hm;
    *(v4f*)(c0s + rr * 260 + f4) = cm;
  }
  __syncthreads();

  v4f acc1[4], acc2[4];
#pragma unroll
  for (int g = 0; g < 4; ++g) {
    int col  = 256 * g + 16 * fi + l15;
    float bb = bi[col] + bh[col];
    acc1[g] = (v4f){bb, bb, bb, bb};
    acc2[g] = (v4f){0.f, 0.f, 0.f, 0.f};
  }
  const int arow = l * KLVL + mf * 16 + l15;
#pragma unroll 1
  for (int kk = 0; kk < 8; ++kk) {   // x @ Wih^T
    const int ko = kk * 32 + lq * 8;
    v4f x0 = *(const v4f*)(emb + (size_t)arow * HIDD + ko);
    v4f x1 = *(const v4f*)(emb + (size_t)arow * HIDD + ko + 4);
    v8h axh, axl;
    split8(x0, x1, axh, axl);
#pragma unroll
    for (int g = 0; g < 4; ++g) {
      int n = 256 * g + 16 * fi + l15;
      v8h bh8 = *(const v8h*)(WihH + (size_t)n * HIDD + ko);
      v8h bl8 = *(const v8h*)(WihL + (size_t)n * HIDD + ko);
      acc1[g] = mfma16(axh, bh8, acc1[g]);
      acc2[g] = mfma16(axl, bh8, acc2[g]);
      acc2[g] = mfma16(axh, bl8, acc2[g]);
    }
  }
#pragma unroll 1
  for (int kk = 0; kk < 8; ++kk) {   // h0 @ Whh^T
    const int ko = kk * 32 + lq * 8;
    v4f h0 = *(const v4f*)(h0s + l15 * 260 + ko);
    v4f h1 = *(const v4f*)(h0s + l15 * 260 + ko + 4);
    v8h ahh, ahl;
    split8(h0, h1, ahh, ahl);
#pragma unroll
    for (int g = 0; g < 4; ++g) {
      int n = 256 * g + 16 * fi + l15;
      v8h bh8 = *(const v8h*)(WhhH + (size_t)n * HIDD + ko);
      v8h bl8 = *(const v8h*)(WhhL + (size_t)n * HIDD + ko);
      acc1[g] = mfma16(ahh, bh8, acc1[g]);
      acc2[g] = mfma16(ahl, bh8, acc2[g]);
      acc2[g] = mfma16(ahh, bl8, acc2[g]);
    }
  }
#pragma unroll
  for (int r = 0; r < 4; ++r) {
    int rr = lq * 4 + r;
    int n  = 16 * fi + l15;
    float ig = acc1[0][r] + acc2[0][r] * INV2048;
    float fg = acc1[1][r] + acc2[1][r] * INV2048;
    float gg = acc1[2][r] + acc2[2][r] * INV2048;
    float og = acc1[3][r] + acc2[3][r] * INV2048;
    float c0 = c0s[rr * 260 + n];
    float cn = fsig(fg) * c0 + fsig(ig) * ftanh(gg);
    float hn = fsig(og) * ftanh(cn);
    int grow = l * KLVL + mf * 16 + rr;
    H[(size_t)grow * HIDD + n] = hn;
    C[(size_t)grow * HIDD + n] = cn;
  }
}

// ---------------- K4a: partial root max (32 blocks x 64 rows) ---------------
__global__ __launch_bounds__(256) void kroot1(const float* __restrict__ H,
                                              const int* __restrict__ appears,
                                              float* __restrict__ pmax) {
  __shared__ int app[64];
  const int tid = threadIdx.x;
  const int rb  = blockIdx.x * 64;
  if (tid < 64) app[tid] = appears[rb + tid];
  __syncthreads();
  float m = -1e30f;
#pragma unroll 1
  for (int r = 0; r < 64; ++r) {
    if (app[r] == 0) m = fmaxf(m, H[(size_t)(rb + r) * HIDD + tid]);
  }
  pmax[blockIdx.x * 256 + tid] = m;
}

// ---------------- K4b: final combine + linear -------------------------------
__global__ __launch_bounds__(256) void kroot2(const float* __restrict__ pmax,
                                              const float* __restrict__ Wlin,
                                              const float* __restrict__ blin,
                                              float* __restrict__ out) {
  __shared__ float red[256];
  const int tid = threadIdx.x;
  float m = pmax[tid];
#pragma unroll 1
  for (int bb = 1; bb < 32; ++bb) m = fmaxf(m, pmax[bb * 256 + tid]);
  red[tid] = m * Wlin[tid];
  __syncthreads();
  if (tid == 0) {
    float s = 0.f;
    for (int i2 = 0; i2 < 256; ++i2) s += red[i2];
    out[0] = s + blin[0];
  }
}

// ---------------- launch ----------------------------------------------------
extern "C" void kernel_launch(void* const* d_in, const int* in_sizes, int n_in,
                              void* d_out, int out_size, void* d_ws, size_t ws_size,
                              hipStream_t stream) {
  const float* tokens  = (const float*)d_in[0];
  const int*   pidx    = (const int*)d_in[1];
  const void*  pvraw   = (const void*)d_in[2];
  const float* Wih_tok = (const float*)d_in[3];
  const float* Whh_tok = (const float*)d_in[4];
  const float* bih_tok = (const float*)d_in[5];
  const float* bhh_tok = (const float*)d_in[6];
  const float* Wih_ins = (const float*)d_in[7];
  const float* Whh_ins = (const float*)d_in[8];
  const float* bih_ins = (const float*)d_in[9];
  const float* bhh_ins = (const float*)d_in[10];
  const float* Wlin    = (const float*)d_in[11];
  const float* blin    = (const float*)d_in[12];

  char* ws = (char*)d_ws;
  const size_t OFF_XG   = 0;                        // 16384*1024*4 (one t-half, reused)
  const size_t OFF_H    = OFF_XG   + 67108864;
  const size_t OFF_C    = OFF_H    + 2097152;
  const size_t OFF_EMB  = OFF_C    + 2097152;
  const size_t OFF_WHH2   = OFF_EMB   + 2097152;    // interleaved 1024*512*2B = 1 MB
  const size_t OFF_WIHI_H = OFF_WHH2   + 1048576;
  const size_t OFF_WIHI_L = OFF_WIHI_H + 524288;
  const size_t OFF_WHHI_H = OFF_WIHI_L + 524288;
  const size_t OFF_WHHI_L = OFF_WHHI_H + 524288;
  const size_t OFF_WT_H   = OFF_WHHI_L + 524288;    // 1024*512*2 = 1048576
  const size_t OFF_WT_L   = OFF_WT_H   + 1048576;
  const size_t OFF_APP  = OFF_WT_L + 1048576;
  const size_t OFF_PMX  = OFF_APP + 8192;
  const size_t OFF_PV8  = OFF_PMX + 32768;

  float*    Xg    = (float*)(ws + OFF_XG);
  float*    Hbuf  = (float*)(ws + OFF_H);
  float*    Cbuf  = (float*)(ws + OFF_C);
  float*    emb   = (float*)(ws + OFF_EMB);
  _Float16* Whh2  = (_Float16*)(ws + OFF_WHH2);
  _Float16* WihIH = (_Float16*)(ws + OFF_WIHI_H);
  _Float16* WihIL = (_Float16*)(ws + OFF_WIHI_L);
  _Float16* WhhIH = (_Float16*)(ws + OFF_WHHI_H);
  _Float16* WhhIL = (_Float16*)(ws + OFF_WHHI_L);
  _Float16* WtH   = (_Float16*)(ws + OFF_WT_H);
  _Float16* WtL   = (_Float16*)(ws + OFF_WT_L);
  int*      app   = (int*)(ws + OFF_APP);
  float*    pmx   = (float*)(ws + OFF_PMX);
  unsigned char* pv8 = (unsigned char*)(ws + OFF_PV8);

  hipMemsetAsync(ws + OFF_APP, 0, 8192, stream);

  knorm<<<dim3(1), dim3(256), 0, stream>>>(pvraw, pv8);
  kw_cvt<<<dim3(3072), dim3(256), 0, stream>>>(Whh_tok, Whh2,
                                               Wih_ins, WihIH, WihIL,
                                               Whh_ins, WhhIH, WhhIL,
                                               Wih_tok, WtH, WtL);
  kapp<<<dim3(32), dim3(256), 0, stream>>>(pidx, pv8, app);
  // half 0: t = 0..7
  kg_gemm<<<dim3(1024), dim3(256), 0, stream>>>(tokens, WtH, WtL, bih_tok, bhh_tok, Xg, 0);
  kr_rec<<<dim3(128), dim3(512), 0, stream>>>(Xg, Whh2, Hbuf, Cbuf, emb, 0);
  // half 1: t = 8..15 (reuses Xg buffer)
  kg_gemm<<<dim3(1024), dim3(256), 0, stream>>>(tokens, WtH, WtL, bih_tok, bhh_tok, Xg, 8);
  kr_rec<<<dim3(128), dim3(512), 0, stream>>>(Xg, Whh2, Hbuf, Cbuf, emb, 1);
  // DAG: one kernel per level
  for (int l = 0; l < NLVL; ++l) {
    klevel<<<dim3(32), dim3(256), 0, stream>>>(emb, WihIH, WihIL, WhhIH, WhhIL,
                                               bih_ins, bhh_ins, pidx, pv8,
                                               Hbuf, Cbuf, l);
  }
  kroot1<<<dim3(32), dim3(256), 0, stream>>>(Hbuf, app, pmx);
  kroot2<<<dim3(1), dim3(256), 0, stream>>>(pmx, Wlin, blin, (float*)d_out);
}

// Round 7
// 731.367 us; speedup vs baseline: 2.2721x; 1.6012x over previous
//
#include <hip/hip_runtime.h>

// ---------------- problem constants ----------------
#define NTOK 2048   // instructions
#define TT   16     // tokens per instruction
#define EE   512    // token embed dim
#define HIDD 256    // hidden
#define G4   1024   // 4*HID gate dim
#define NLVL 16
#define KLVL 128    // instrs per level
#define INV2048 (1.0f/2048.0f)

typedef _Float16 v8h __attribute__((ext_vector_type(8)));
typedef _Float16 v4h __attribute__((ext_vector_type(4)));
typedef float    v4f __attribute__((ext_vector_type(4)));

__device__ __forceinline__ v4f mfma16(v8h a, v8h b, v4f c) {
  return __builtin_amdgcn_mfma_f32_16x16x32_f16(a, b, c, 0, 0, 0);
}

__device__ __forceinline__ float fsig(float x) {
  return 1.0f / (1.0f + __expf(-x));
}
__device__ __forceinline__ float ftanh(float x) {
  float ax = fabsf(x);
  float e  = __expf(-2.0f * ax);
  float t  = (1.0f - e) / (1.0f + e);
  return copysignf(t, x);
}

// split fp32 -> (hi fp16, lo fp16 scaled by 2048)
__device__ __forceinline__ void split8(const v4f& w0, const v4f& w1, v8h& hi, v8h& lo) {
#pragma unroll
  for (int u = 0; u < 4; ++u) {
    float v = w0[u]; _Float16 h = (_Float16)v;
    hi[u] = h; lo[u] = (_Float16)((v - (float)h) * 2048.0f);
  }
#pragma unroll
  for (int u = 0; u < 4; ++u) {
    float v = w1[u]; _Float16 h = (_Float16)v;
    hi[4+u] = h; lo[4+u] = (_Float16)((v - (float)h) * 2048.0f);
  }
}

// ---------------- K-1: normalize parent_valid to uchar[16384] ---------------
__global__ __launch_bounds__(256) void knorm(const void* __restrict__ pv_raw,
                                             unsigned char* __restrict__ pv8) {
  __shared__ int mode;   // 0 = int32, 1 = bytes, 2 = float32
  const int tid = threadIdx.x;
  if (tid == 0) mode = 0;
  __syncthreads();
  const unsigned* pu = (const unsigned*)pv_raw;
  int local = 0;
  for (int i = tid; i < 4096; i += 256) {
    unsigned v = pu[i];
    if (v == 0x3F800000u) { local = 2; break; }
    if (v > 1u) local = 1;
  }
  if (local) atomicMax(&mode, local);
  __syncthreads();
  const int m = mode;
  const unsigned char* pb = (const unsigned char*)pv_raw;
  const float* pf = (const float*)pv_raw;
  const int* pi = (const int*)pv_raw;
  for (int i = tid; i < NTOK * 8; i += 256) {
    unsigned char v;
    if (m == 1)      v = (pb[i] != 0);
    else if (m == 2) v = (pf[i] != 0.0f);
    else             v = (pi[i] != 0);
    pv8[i] = v;
  }
}

// ---------------- K0: weight splits -----------------------------------------
// Fragment-major packing for [1024][256] matrices (Whh_tok, Wih_ins, Whh_ins):
//   row = 16*fc + l15, col = kk*32 + lq*8 + u, lane = lq*16 + l15
//   dst[(fc*8+kk)*1024 + lane*8 + u] = hi;  dst[... + 512] = lo (halves)
// One wave B-fragment load = contiguous 1 KB.  Wih_tok stays flat hi/lo.
__global__ __launch_bounds__(256) void kw_cvt(
    const float* __restrict__ a0, _Float16* __restrict__ f0,
    const float* __restrict__ a1, _Float16* __restrict__ f1,
    const float* __restrict__ a2, _Float16* __restrict__ f2,
    const float* __restrict__ a3, _Float16* __restrict__ h3, _Float16* __restrict__ l3) {
  int i = blockIdx.x * 256 + threadIdx.x;
  if (blockIdx.x < 1024) {
    const int row = i >> 8, col = i & 255;
    const int fc = row >> 4, l15 = row & 15;
    const int kk = col >> 5, lq = (col >> 3) & 3, u = col & 7;
    const size_t base = (size_t)(fc * 8 + kk) * 1024 + (lq * 16 + l15) * 8 + u;
    float v; _Float16 h;
    v = a0[i]; h = (_Float16)v; f0[base] = h; f0[base + 512] = (_Float16)((v - (float)h) * 2048.0f);
    v = a1[i]; h = (_Float16)v; f1[base] = h; f1[base + 512] = (_Float16)((v - (float)h) * 2048.0f);
    v = a2[i]; h = (_Float16)v; f2[base] = h; f2[base + 512] = (_Float16)((v - (float)h) * 2048.0f);
  } else {
    int k = i - 262144;            // 0..524287
    float v = a3[k]; _Float16 h = (_Float16)v;
    h3[k] = h; l3[k] = (_Float16)((v - (float)h) * 2048.0f);
  }
}

// ---------------- K1: Xg = tokens @ Wih_tok^T (+biases), fp32, tiled layout --
// GEMM M-order: ar = t_local*2048 + instr; store Xg[((ar>>2)*G4 + col)*4 + (ar&3)].
__global__ __launch_bounds__(256, 2) void kg_gemm(const float* __restrict__ A,
                                                  const _Float16* __restrict__ WtH,
                                                  const _Float16* __restrict__ WtL,
                                                  const float* __restrict__ b1,
                                                  const float* __restrict__ b2,
                                                  float* __restrict__ Xg, int t0) {
  __shared__ _Float16 AsH[128 * 72];
  __shared__ _Float16 AsL[128 * 72];
  __shared__ _Float16 BsH[128 * 72];
  __shared__ _Float16 BsL[128 * 72];
  const int tid  = threadIdx.x;
  const int lane = tid & 63;
  const int wv   = tid >> 6;
  const int wr   = (wv >> 1) * 64;
  const int wc   = (wv & 1) * 64;
  const int mb   = blockIdx.x >> 3;
  const int nb   = blockIdx.x & 7;
  const int row0 = mb * 128;
  const int col0 = nb * 128;
  const int l15  = lane & 15;
  const int lq   = lane >> 4;
  const int tglob = (row0 >> 11) + t0;
  const int ib0   = row0 & 2047;

  v4f acc1[4][4], acc2[4][4];
#pragma unroll
  for (int n = 0; n < 4; ++n) {
    int col  = col0 + wc + n * 16 + l15;
    float bb = b1[col] + b2[col];
#pragma unroll
    for (int m = 0; m < 4; ++m) { acc1[m][n] = (v4f){bb, bb, bb, bb}; acc2[m][n] = (v4f){0.f,0.f,0.f,0.f}; }
  }

#pragma unroll 1
  for (int kt = 0; kt < 8; ++kt) {
    const int k0 = kt * 64;
#pragma unroll
    for (int i = 0; i < 8; ++i) {
      int chunk = tid + 256 * i;
      int r  = chunk >> 4;
      int c4 = (chunk & 15) * 4;
      int tokrow = (ib0 + r) * 16 + tglob;
      v4f av = *(const v4f*)(A + (size_t)tokrow * EE + k0 + c4);
      v4h ah, al;
#pragma unroll
      for (int u = 0; u < 4; ++u) {
        float v = av[u]; _Float16 h = (_Float16)v;
        ah[u] = h; al[u] = (_Float16)((v - (float)h) * 2048.0f);
      }
      *(v4h*)(AsH + r * 72 + c4) = ah;
      *(v4h*)(AsL + r * 72 + c4) = al;
    }
#pragma unroll
    for (int i = 0; i < 4; ++i) {
      int chunk = tid + 256 * i;
      int r  = chunk >> 3;
      int c8 = (chunk & 7) * 8;
      *(v8h*)(BsH + r * 72 + c8) = *(const v8h*)(WtH + (size_t)(col0 + r) * EE + k0 + c8);
      *(v8h*)(BsL + r * 72 + c8) = *(const v8h*)(WtL + (size_t)(col0 + r) * EE + k0 + c8);
    }
    __syncthreads();
#pragma unroll
    for (int kk = 0; kk < 2; ++kk) {
      const int ko = kk * 32 + lq * 8;
      v8h afh[4], afl[4], bfh[4], bfl[4];
#pragma unroll
      for (int m = 0; m < 4; ++m) {
        afh[m] = *(const v8h*)(AsH + (wr + m * 16 + l15) * 72 + ko);
        afl[m] = *(const v8h*)(AsL + (wr + m * 16 + l15) * 72 + ko);
      }
#pragma unroll
      for (int n = 0; n < 4; ++n) {
        bfh[n] = *(const v8h*)(BsH + (wc + n * 16 + l15) * 72 + ko);
        bfl[n] = *(const v8h*)(BsL + (wc + n * 16 + l15) * 72 + ko);
      }
#pragma unroll
      for (int m = 0; m < 4; ++m)
#pragma unroll
        for (int n = 0; n < 4; ++n) {
          acc1[m][n] = mfma16(afh[m], bfh[n], acc1[m][n]);
          acc2[m][n] = mfma16(afl[m], bfh[n], acc2[m][n]);
          acc2[m][n] = mfma16(afh[m], bfl[n], acc2[m][n]);
        }
    }
    __syncthreads();
  }

#pragma unroll
  for (int m = 0; m < 4; ++m)
#pragma unroll
    for (int n = 0; n < 4; ++n) {
      int row = row0 + wr + m * 16 + lq * 4;
      int col = col0 + wc + n * 16 + l15;
      v4f o;
#pragma unroll
      for (int r = 0; r < 4; ++r) o[r] = acc1[m][n][r] + acc2[m][n][r] * INV2048;
      *(v4f*)(Xg + ((size_t)(row >> 2) * G4 + col) * 4) = o;
    }
}

// ---------------- K2: token LSTM recurrence, 8 steps per half ---------------
// 128 blocks x 16 rows x 8 waves; kk-split across wave halves; fragment-packed
// Whh (coalesced 1KB B-loads).
__global__ __launch_bounds__(512, 2) void kr_rec(const float* __restrict__ Xg,
                                                 const _Float16* __restrict__ WhhF,
                                                 float* __restrict__ Hst,
                                                 float* __restrict__ Cst,
                                                 float* __restrict__ emb, int half) {
  __shared__ float hbuf[16 * 260];
  __shared__ v4f red[4][16][64];   // [wv][g*4+j][lane] : 64 KB
  const int tid  = threadIdx.x;
  const int lane = tid & 63;
  const int w    = tid >> 6;       // 0..7
  const int wv   = w & 3;
  const int kkh  = w >> 2;         // 0: kk 0-3, 1: kk 4-7
  const int l15  = lane & 15;
  const int lq   = lane >> 4;
  const int r0   = blockIdx.x * 16;

  v4f c[4];
  if (kkh == 0) {
    if (half) {
#pragma unroll
      for (int j = 0; j < 4; ++j) {
        const int feat = 16 * (wv + 4 * j) + l15;
#pragma unroll
        for (int r = 0; r < 4; ++r)
          c[j][r] = Cst[(size_t)(r0 + lq * 4 + r) * HIDD + feat];
      }
    } else {
#pragma unroll
      for (int j = 0; j < 4; ++j) c[j] = (v4f){0.f, 0.f, 0.f, 0.f};
    }
  }
  if (half) {
    for (int idx = tid; idx < 4096; idx += 512)
      hbuf[(idx >> 8) * 260 + (idx & 255)] = Hst[(size_t)(r0 + (idx >> 8)) * HIDD + (idx & 255)];
  }
  __syncthreads();

#pragma unroll 1
  for (int tl = 0; tl < 8; ++tl) {
    const bool have_h = half || (tl > 0);
    v4f acc1[4][4], acc2[4][4];
    if (kkh == 0) {
      const size_t xrow = (size_t)(tl * 512 + (r0 >> 2) + lq) * G4;
#pragma unroll
      for (int g = 0; g < 4; ++g)
#pragma unroll
        for (int j = 0; j < 4; ++j) {
          const int col = 256 * g + 16 * (wv + 4 * j) + l15;
          acc1[g][j] = *(const v4f*)(Xg + (xrow + col) * 4);
          acc2[g][j] = (v4f){0.f, 0.f, 0.f, 0.f};
        }
    } else {
#pragma unroll
      for (int g = 0; g < 4; ++g)
#pragma unroll
        for (int j = 0; j < 4; ++j) {
          acc1[g][j] = (v4f){0.f, 0.f, 0.f, 0.f};
          acc2[g][j] = (v4f){0.f, 0.f, 0.f, 0.f};
        }
    }
    if (have_h) {
#pragma unroll 1
      for (int kk2 = 0; kk2 < 4; ++kk2) {
        const int kk = kkh * 4 + kk2;
        const int ko = kk * 32 + lq * 8;
        v4f w0 = *(const v4f*)(hbuf + l15 * 260 + ko);
        v4f w1 = *(const v4f*)(hbuf + l15 * 260 + ko + 4);
        v8h ah, al;
        split8(w0, w1, ah, al);
#pragma unroll
        for (int g = 0; g < 4; ++g)
#pragma unroll
          for (int j = 0; j < 4; ++j) {
            const int fc = 16 * g + wv + 4 * j;
            const _Float16* p = WhhF + (size_t)(fc * 8 + kk) * 1024 + lane * 8;
            v8h bh = *(const v8h*)p;
            v8h bl = *(const v8h*)(p + 512);
            acc1[g][j] = mfma16(ah, bh, acc1[g][j]);
            acc2[g][j] = mfma16(al, bh, acc2[g][j]);
            acc2[g][j] = mfma16(ah, bl, acc2[g][j]);
          }
      }
    }
    if (kkh == 1) {
#pragma unroll
      for (int g = 0; g < 4; ++g)
#pragma unroll
        for (int j = 0; j < 4; ++j)
          red[wv][g * 4 + j][lane] = acc1[g][j] + acc2[g][j] * INV2048;
    }
    __syncthreads();   // red written; all hbuf reads complete
    if (kkh == 0) {
#pragma unroll
      for (int j = 0; j < 4; ++j) {
        const int feat = 16 * (wv + 4 * j) + l15;
        v4f si = acc1[0][j] + acc2[0][j] * INV2048 + red[wv][0 * 4 + j][lane];
        v4f sf = acc1[1][j] + acc2[1][j] * INV2048 + red[wv][1 * 4 + j][lane];
        v4f sg = acc1[2][j] + acc2[2][j] * INV2048 + red[wv][2 * 4 + j][lane];
        v4f so = acc1[3][j] + acc2[3][j] * INV2048 + red[wv][3 * 4 + j][lane];
#pragma unroll
        for (int r = 0; r < 4; ++r) {
          const int rr = lq * 4 + r;
          float cn = fsig(sf[r]) * c[j][r] + fsig(si[r]) * ftanh(sg[r]);
          float hn = fsig(so[r]) * ftanh(cn);
          c[j][r] = cn;
          hbuf[rr * 260 + feat] = hn;
          if (tl == 7) {
            const size_t grow = r0 + rr;
            if (!half) { Hst[grow * HIDD + feat] = hn; Cst[grow * HIDD + feat] = cn; }
            else       { emb[grow * HIDD + feat] = hn; }
          }
        }
      }
    }
    __syncthreads();   // hbuf writes visible before next step's reads
  }
}

// ---------------- K3a: appears scatter (32 blocks) --------------------------
__global__ __launch_bounds__(256) void kapp(const int* __restrict__ pidx,
                                            const unsigned char* __restrict__ pval,
                                            int* __restrict__ appears) {
  int e = blockIdx.x * 512 + threadIdx.x * 2;
#pragma unroll
  for (int u = 0; u < 2; ++u, ++e) {
    if (pval[e]) atomicAdd(appears + pidx[e], 1);
  }
}

// ---------------- K3b: one DAG level (32 blocks) ----------------------------
// Fragment-packed WihF/WhhF (coalesced 1KB B-loads).
__global__ __launch_bounds__(256) void klevel(
    const float* __restrict__ emb,
    const _Float16* __restrict__ WihF, const _Float16* __restrict__ WhhF,
    const float* __restrict__ bi, const float* __restrict__ bh,
    const int* __restrict__ pidx, const unsigned char* __restrict__ pval,
    float* __restrict__ H, float* __restrict__ C, int l) {
  __shared__ float h0s[16 * 260];
  __shared__ float c0s[16 * 260];
  __shared__ int      pis[128];
  __shared__ unsigned char pvs[128];
  const int tid  = threadIdx.x;
  const int lane = tid & 63;
  const int wv   = tid >> 6;
  const int l15  = lane & 15;
  const int lq   = lane >> 4;
  const int b    = blockIdx.x;
  const int mf   = b >> 2;
  const int q    = b & 3;
  const int fi   = q * 4 + wv;

  if (tid < 128) {
    int rr = tid >> 3, p = tid & 7;
    int row = l * KLVL + mf * 16 + rr;
    pis[tid] = pidx[row * 8 + p];
    pvs[tid] = pval[row * 8 + p];
  }
  __syncthreads();
#pragma unroll 1
  for (int it = 0; it < 4; ++it) {
    int task = tid + 256 * it;
    int rr = task >> 6;
    int f4 = (task & 63) * 4;
    v4f hm = (v4f){-1e30f, -1e30f, -1e30f, -1e30f};
    v4f cm = hm;
    bool any = false;
#pragma unroll
    for (int p = 0; p < 8; ++p) {
      if (pvs[rr * 8 + p]) {
        any = true;
        int par = pis[rr * 8 + p];
        v4f hv = *(const v4f*)(H + (size_t)par * HIDD + f4);
        v4f cv = *(const v4f*)(C + (size_t)par * HIDD + f4);
#pragma unroll
        for (int u = 0; u < 4; ++u) { hm[u] = fmaxf(hm[u], hv[u]); cm[u] = fmaxf(cm[u], cv[u]); }
      }
    }
    if (!any) { hm = (v4f){0.f,0.f,0.f,0.f}; cm = (v4f){0.f,0.f,0.f,0.f}; }
    *(v4f*)(h0s + rr * 260 + f4) = hm;
    *(v4f*)(c0s + rr * 260 + f4) = cm;
  }
  __syncthreads();

  v4f acc1[4], acc2[4];
#pragma unroll
  for (int g = 0; g < 4; ++g) {
    int col  = 256 * g + 16 * fi + l15;
    float bb = bi[col] + bh[col];
    acc1[g] = (v4f){bb, bb, bb, bb};
    acc2[g] = (v4f){0.f, 0.f, 0.f, 0.f};
  }
  const int arow = l * KLVL + mf * 16 + l15;
#pragma unroll 1
  for (int kk = 0; kk < 8; ++kk) {   // x @ Wih^T
    const int ko = kk * 32 + lq * 8;
    v4f x0 = *(const v4f*)(emb + (size_t)arow * HIDD + ko);
    v4f x1 = *(const v4f*)(emb + (size_t)arow * HIDD + ko + 4);
    v8h axh, axl;
    split8(x0, x1, axh, axl);
#pragma unroll
    for (int g = 0; g < 4; ++g) {
      const int fc = 16 * g + fi;
      const _Float16* p = WihF + (size_t)(fc * 8 + kk) * 1024 + lane * 8;
      v8h bh8 = *(const v8h*)p;
      v8h bl8 = *(const v8h*)(p + 512);
      acc1[g] = mfma16(axh, bh8, acc1[g]);
      acc2[g] = mfma16(axl, bh8, acc2[g]);
      acc2[g] = mfma16(axh, bl8, acc2[g]);
    }
  }
#pragma unroll 1
  for (int kk = 0; kk < 8; ++kk) {   // h0 @ Whh^T
    const int ko = kk * 32 + lq * 8;
    v4f h0 = *(const v4f*)(h0s + l15 * 260 + ko);
    v4f h1 = *(const v4f*)(h0s + l15 * 260 + ko + 4);
    v8h ahh, ahl;
    split8(h0, h1, ahh, ahl);
#pragma unroll
    for (int g = 0; g < 4; ++g) {
      const int fc = 16 * g + fi;
      const _Float16* p = WhhF + (size_t)(fc * 8 + kk) * 1024 + lane * 8;
      v8h bh8 = *(const v8h*)p;
      v8h bl8 = *(const v8h*)(p + 512);
      acc1[g] = mfma16(ahh, bh8, acc1[g]);
      acc2[g] = mfma16(ahl, bh8, acc2[g]);
      acc2[g] = mfma16(ahh, bl8, acc2[g]);
    }
  }
#pragma unroll
  for (int r = 0; r < 4; ++r) {
    int rr = lq * 4 + r;
    int n  = 16 * fi + l15;
    float ig = acc1[0][r] + acc2[0][r] * INV2048;
    float fg = acc1[1][r] + acc2[1][r] * INV2048;
    float gg = acc1[2][r] + acc2[2][r] * INV2048;
    float og = acc1[3][r] + acc2[3][r] * INV2048;
    float c0 = c0s[rr * 260 + n];
    float cn = fsig(fg) * c0 + fsig(ig) * ftanh(gg);
    float hn = fsig(og) * ftanh(cn);
    int grow = l * KLVL + mf * 16 + rr;
    H[(size_t)grow * HIDD + n] = hn;
    C[(size_t)grow * HIDD + n] = cn;
  }
}

// ---------------- K4a: partial root max (32 blocks x 64 rows) ---------------
__global__ __launch_bounds__(256) void kroot1(const float* __restrict__ H,
                                              const int* __restrict__ appears,
                                              float* __restrict__ pmax) {
  __shared__ int app[64];
  const int tid = threadIdx.x;
  const int rb  = blockIdx.x * 64;
  if (tid < 64) app[tid] = appears[rb + tid];
  __syncthreads();
  float m = -1e30f;
#pragma unroll 1
  for (int r = 0; r < 64; ++r) {
    if (app[r] == 0) m = fmaxf(m, H[(size_t)(rb + r) * HIDD + tid]);
  }
  pmax[blockIdx.x * 256 + tid] = m;
}

// ---------------- K4b: final combine + linear -------------------------------
__global__ __launch_bounds__(256) void kroot2(const float* __restrict__ pmax,
                                              const float* __restrict__ Wlin,
                                              const float* __restrict__ blin,
                                              float* __restrict__ out) {
  __shared__ float red[256];
  const int tid = threadIdx.x;
  float m = pmax[tid];
#pragma unroll 1
  for (int bb = 1; bb < 32; ++bb) m = fmaxf(m, pmax[bb * 256 + tid]);
  red[tid] = m * Wlin[tid];
  __syncthreads();
  if (tid == 0) {
    float s = 0.f;
    for (int i2 = 0; i2 < 256; ++i2) s += red[i2];
    out[0] = s + blin[0];
  }
}

// ---------------- launch ----------------------------------------------------
extern "C" void kernel_launch(void* const* d_in, const int* in_sizes, int n_in,
                              void* d_out, int out_size, void* d_ws, size_t ws_size,
                              hipStream_t stream) {
  const float* tokens  = (const float*)d_in[0];
  const int*   pidx    = (const int*)d_in[1];
  const void*  pvraw   = (const void*)d_in[2];
  const float* Wih_tok = (const float*)d_in[3];
  const float* Whh_tok = (const float*)d_in[4];
  const float* bih_tok = (const float*)d_in[5];
  const float* bhh_tok = (const float*)d_in[6];
  const float* Wih_ins = (const float*)d_in[7];
  const float* Whh_ins = (const float*)d_in[8];
  const float* bih_ins = (const float*)d_in[9];
  const float* bhh_ins = (const float*)d_in[10];
  const float* Wlin    = (const float*)d_in[11];
  const float* blin    = (const float*)d_in[12];

  char* ws = (char*)d_ws;
  const size_t OFF_XG   = 0;                        // 16384*1024*4 (one t-half, reused)
  const size_t OFF_H    = OFF_XG   + 67108864;
  const size_t OFF_C    = OFF_H    + 2097152;
  const size_t OFF_EMB  = OFF_C    + 2097152;
  const size_t OFF_WHHF  = OFF_EMB   + 2097152;     // packed 1 MB each
  const size_t OFF_WIHIF = OFF_WHHF  + 1048576;
  const size_t OFF_WHHIF = OFF_WIHIF + 1048576;
  const size_t OFF_WT_H  = OFF_WHHIF + 1048576;     // 1024*512*2 = 1048576
  const size_t OFF_WT_L  = OFF_WT_H  + 1048576;
  const size_t OFF_APP  = OFF_WT_L + 1048576;
  const size_t OFF_PMX  = OFF_APP + 8192;
  const size_t OFF_PV8  = OFF_PMX + 32768;

  float*    Xg    = (float*)(ws + OFF_XG);
  float*    Hbuf  = (float*)(ws + OFF_H);
  float*    Cbuf  = (float*)(ws + OFF_C);
  float*    emb   = (float*)(ws + OFF_EMB);
  _Float16* WhhF  = (_Float16*)(ws + OFF_WHHF);
  _Float16* WihIF = (_Float16*)(ws + OFF_WIHIF);
  _Float16* WhhIF = (_Float16*)(ws + OFF_WHHIF);
  _Float16* WtH   = (_Float16*)(ws + OFF_WT_H);
  _Float16* WtL   = (_Float16*)(ws + OFF_WT_L);
  int*      app   = (int*)(ws + OFF_APP);
  float*    pmx   = (float*)(ws + OFF_PMX);
  unsigned char* pv8 = (unsigned char*)(ws + OFF_PV8);

  hipMemsetAsync(ws + OFF_APP, 0, 8192, stream);

  knorm<<<dim3(1), dim3(256), 0, stream>>>(pvraw, pv8);
  kw_cvt<<<dim3(3072), dim3(256), 0, stream>>>(Whh_tok, WhhF,
                                               Wih_ins, WihIF,
                                               Whh_ins, WhhIF,
                                               Wih_tok, WtH, WtL);
  kapp<<<dim3(32), dim3(256), 0, stream>>>(pidx, pv8, app);
  // half 0: t = 0..7
  kg_gemm<<<dim3(1024), dim3(256), 0, stream>>>(tokens, WtH, WtL, bih_tok, bhh_tok, Xg, 0);
  kr_rec<<<dim3(128), dim3(512), 0, stream>>>(Xg, WhhF, Hbuf, Cbuf, emb, 0);
  // half 1: t = 8..15 (reuses Xg buffer)
  kg_gemm<<<dim3(1024), dim3(256), 0, stream>>>(tokens, WtH, WtL, bih_tok, bhh_tok, Xg, 8);
  kr_rec<<<dim3(128), dim3(512), 0, stream>>>(Xg, WhhF, Hbuf, Cbuf, emb, 1);
  // DAG: one kernel per level
  for (int l = 0; l < NLVL; ++l) {
    klevel<<<dim3(32), dim3(256), 0, stream>>>(emb, WihIF, WhhIF,
                                               bih_ins, bhh_ins, pidx, pv8,
                                               Hbuf, Cbuf, l);
  }
  kroot1<<<dim3(32), dim3(256), 0, stream>>>(Hbuf, app, pmx);
  kroot2<<<dim3(1), dim3(256), 0, stream>>>(pmx, Wlin, blin, (float*)d_out);
}